// Round 4
// baseline (513.934 us; speedup 1.0000x reference)
//
#include <hip/hip_runtime.h>
#include <cstddef>

#define TPB 256

typedef __attribute__((ext_vector_type(8))) short short8;
typedef __attribute__((ext_vector_type(4))) float f32x4;

__device__ inline unsigned short f2bf(float f) {
    unsigned int u = __builtin_bit_cast(unsigned int, f);
    u += 0x7fffu + ((u >> 16) & 1u);
    return (unsigned short)(u >> 16);
}
__device__ inline float bf2f(unsigned short h) {
    unsigned int u = ((unsigned int)h) << 16;
    return __builtin_bit_cast(float, u);
}

struct TapOffs { int o[9]; };

// ---------------------------------------------------------------------------
// LDS-staged 3x3 conv GEMM. Block tile: 64x4 pixels (256 m) x 64 n, 4 waves,
// wave w = pixel row w; per wave MW=4 m-frags x NT=4 n-frags = 32 MFMA per
// 16 ds_read_b128 per tap-chunk. A-tile (66x6 px, 64-ch chunk, stride 72 for
// bank-conflict-free reads) staged once, read by all 9 taps. B double-buffered
// in LDS (packed fragment order), 1 barrier per tap. K chunked by 64 channels.
// mfma_f32_16x16x32_bf16: A[m=lane&15][k=(lane>>4)*8+j], B[k][n=lane&15],
// D: col(n)=lane&15, row(m)=(lane>>4)*4+reg.
// ---------------------------------------------------------------------------
template<int CHUNKS>   // input channels = CHUNKS*64
__global__ __launch_bounds__(TPB) void k_conv3(
    const unsigned short* __restrict__ A0, const unsigned short* __restrict__ Wf,
    const float* __restrict__ bias, unsigned short* __restrict__ O0,
    int AP, int tilesX, int OMS, int OP, int NTtot)
{
    constexpr int Cs  = CHUNKS * 64;
    constexpr int KC2 = CHUNKS * 2;      // total q-steps (k32) per tap
    __shared__ unsigned short As[6 * 66 * 72];    // 57,024 B
    __shared__ unsigned short Bs[2][4096];        // 16,384 B

    int lane = threadIdx.x & 63, wave = threadIdx.x >> 6;
    int ml = lane & 15, kq = lane >> 4;
    int nb = blockIdx.y;
    int tileX = blockIdx.x % tilesX, tileY = blockIdx.x / tilesX;
    int gx0 = tileX * 64, gy0 = tileY * 4;

    f32x4 acc[4][4];
    #pragma unroll
    for (int mf = 0; mf < 4; ++mf)
        #pragma unroll
        for (int nt = 0; nt < 4; ++nt) acc[mf][nt] = (f32x4){0.f, 0.f, 0.f, 0.f};

    for (int ch = 0; ch < CHUNKS; ++ch) {
        // ---- stage A chunk (incl. 1-px halo; padded input ring is valid) ----
        {
            const unsigned short* Ab = A0 + (size_t)(gy0 - 1) * AP
                                          + (size_t)(gx0 - 1) * Cs + ch * 64;
            for (int u = threadIdx.x; u < 6 * 66 * 8; u += TPB) {
                int row = u / 528;
                int rem = u - row * 528;
                int px = rem >> 3, c16 = rem & 7;
                int4 v = *(const int4*)(Ab + (size_t)row * AP + (size_t)px * Cs + c16 * 8);
                *(int4*)&As[(row * 66 + px) * 72 + c16 * 8] = v;
            }
        }
        // ---- stage B(tap=0) into buf 0 ----
        {
            const unsigned short* bsrc = Wf + ((size_t)(ch * 2) * NTtot + nb * 4) * 512;
            for (int u = threadIdx.x; u < 512; u += TPB) {
                int q = u >> 8, r = u & 255;
                int4 v = *(const int4*)(bsrc + (size_t)q * NTtot * 512 + r * 8);
                *(int4*)&Bs[0][q * 2048 + r * 8] = v;
            }
        }
        __syncthreads();

        for (int tap = 0; tap < 9; ++tap) {
            if (tap < 8) {   // prefetch next tap's B into the other buffer
                const unsigned short* bsrc = Wf
                    + ((size_t)((tap + 1) * KC2 + ch * 2) * NTtot + nb * 4) * 512;
                unsigned short* bd = Bs[(tap + 1) & 1];
                for (int u = threadIdx.x; u < 512; u += TPB) {
                    int q = u >> 8, r = u & 255;
                    int4 v = *(const int4*)(bsrc + (size_t)q * NTtot * 512 + r * 8);
                    *(int4*)&bd[q * 2048 + r * 8] = v;
                }
            }
            {
                int ky = tap / 3, kx = tap - (tap / 3) * 3;
                const unsigned short* Arow = &As[((wave + ky) * 66 + kx) * 72];
                const unsigned short* Bb = &Bs[tap & 1][lane * 8];
                #pragma unroll
                for (int q = 0; q < 2; ++q) {
                    short8 b[4];
                    #pragma unroll
                    for (int nt = 0; nt < 4; ++nt)
                        b[nt] = *(const short8*)(Bb + q * 2048 + nt * 512);
                    short8 a[4];
                    #pragma unroll
                    for (int mf = 0; mf < 4; ++mf)
                        a[mf] = *(const short8*)(Arow + (mf * 16 + ml) * 72 + q * 32 + kq * 8);
                    #pragma unroll
                    for (int mf = 0; mf < 4; ++mf)
                        #pragma unroll
                        for (int nt = 0; nt < 4; ++nt)
                            acc[mf][nt] = __builtin_amdgcn_mfma_f32_16x16x32_bf16(a[mf], b[nt], acc[mf][nt], 0, 0, 0);
                }
            }
            __syncthreads();
        }
    }

    // ---- epilogue: bias + relu, scatter to channels-last ----
    int gy = gy0 + wave;
    unsigned short* Orow = O0 + (size_t)gy * OP + (size_t)nb * 64;
    #pragma unroll
    for (int mf = 0; mf < 4; ++mf) {
        int gx = gx0 + mf * 16 + kq * 4;
        #pragma unroll
        for (int nt = 0; nt < 4; ++nt) {
            float bv = bias[nb * 64 + nt * 16 + ml];
            #pragma unroll
            for (int r = 0; r < 4; ++r) {
                float v = fmaxf(acc[mf][nt][r] + bv, 0.f);
                Orow[(size_t)(gx + r) * OMS + nt * 16 + ml] = f2bf(v);
            }
        }
    }
}

// ---------------------------------------------------------------------------
// Generic MFMA GEMM (global-direct), MW m-frags per wave. Used for conv1,
// convT (ct=1: blockIdx.z = tap, parity-shifted output) and GNN matmuls.
// ---------------------------------------------------------------------------
template<int MW, int KC>
__global__ __launch_bounds__(TPB) void k_gemm(
    const unsigned short* __restrict__ A0, const unsigned short* __restrict__ Wf,
    const float* __restrict__ bias, const unsigned short* __restrict__ resid, int RS,
    unsigned short* __restrict__ O0,
    int Cs, int AP, int Wimg, int OMS, int OP,
    int T, TapOffs toffs, int NTtot, int relu, int ct, int ctDy, int ctDx)
{
    int lane = threadIdx.x & 63, wave = threadIdx.x >> 6;
    int ml = lane & 15, kq = lane >> 4;
    int nb = blockIdx.y;

    const unsigned short* Wb = Wf;
    unsigned short* Ob = O0;
    if (ct) {
        int tp = blockIdx.z;
        Wb += (size_t)(tp * KC) * NTtot * 512;
        int dy = 1 - (tp >> 1), dx = 1 - (tp & 1);   // jax conv_transpose tap flip
        Ob += (size_t)dy * ctDy + (size_t)dx * ctDx;
    }
    const unsigned short* WbB = Wb + (size_t)(nb * 4) * 512 + lane * 8;

    int fy[MW], fx[MW];
    const unsigned short* Af[MW];
    #pragma unroll
    for (int f = 0; f < MW; ++f) {
        int mf = (blockIdx.x * 4 + wave) * (16 * MW) + f * 16;
        int y = mf / Wimg, x = mf - y * Wimg;
        fy[f] = y; fx[f] = x;
        Af[f] = A0 + (size_t)y * AP + (size_t)(x + ml) * Cs + kq * 8;
    }

    f32x4 acc[MW][4];
    #pragma unroll
    for (int f = 0; f < MW; ++f)
        #pragma unroll
        for (int nt = 0; nt < 4; ++nt) acc[f][nt] = (f32x4){0.f, 0.f, 0.f, 0.f};

    for (int tp = 0; tp < T; ++tp) {
        int toff = toffs.o[tp];
        const unsigned short* Wt = WbB + (size_t)(tp * KC) * NTtot * 512;
        #pragma unroll
        for (int q = 0; q < KC; ++q) {
            short8 b[4];
            #pragma unroll
            for (int nt = 0; nt < 4; ++nt)
                b[nt] = *(const short8*)(Wt + (size_t)q * NTtot * 512 + nt * 512);
            short8 a[MW];
            #pragma unroll
            for (int f = 0; f < MW; ++f)
                a[f] = *(const short8*)(Af[f] + toff + q * 32);
            #pragma unroll
            for (int f = 0; f < MW; ++f)
                #pragma unroll
                for (int nt = 0; nt < 4; ++nt)
                    acc[f][nt] = __builtin_amdgcn_mfma_f32_16x16x32_bf16(a[f], b[nt], acc[f][nt], 0, 0, 0);
        }
    }

    #pragma unroll
    for (int f = 0; f < MW; ++f) {
        unsigned short* Ot = Ob + (size_t)fy[f] * OP + (size_t)(fx[f] + kq * 4) * OMS + (size_t)nb * 64;
        int mg0 = (blockIdx.x * 4 + wave) * (16 * MW) + f * 16 + kq * 4;
        #pragma unroll
        for (int nt = 0; nt < 4; ++nt) {
            int ng = nb * 64 + nt * 16 + ml;
            float bv = bias[ng];
            #pragma unroll
            for (int r = 0; r < 4; ++r) {
                float v = acc[f][nt][r] + bv;
                if (relu) v = fmaxf(v, 0.f);
                if (resid) v += bf2f(resid[(size_t)(mg0 + r) * RS + ng]);
                Ot[(size_t)r * OMS + nt * 16 + ml] = f2bf(v);
            }
        }
    }
}

// ---------------- fused weight packing (all 15 tensors, one dispatch) -------
struct PackArgs {
    const float* w[15];
    int cum[16];
    int mode[15], KC[15], NT[15], K[15], N[15];
};
__global__ __launch_bounds__(TPB) void k_pack_all(
    PackArgs pa, unsigned short* __restrict__ dst, int total)
{
    int idx = blockIdx.x * TPB + threadIdx.x;
    if (idx >= total) return;
    int e = 0;
    #pragma unroll
    for (int i = 1; i < 15; ++i) e += (idx >= pa.cum[i]);
    int local = idx - pa.cum[e];
    const float* w = pa.w[e];
    int KC = pa.KC[e], NT = pa.NT[e], K = pa.K[e], N = pa.N[e], mode = pa.mode[e];

    int j = local & 7, l = (local >> 3) & 63;
    int r = local >> 9;
    int ntg = r % NT; int r2 = r / NT;
    int q = r2 % KC; int tp = r2 / KC;
    int k = q * 32 + (l >> 4) * 8 + j;
    int n = ntg * 16 + (l & 15);
    float v = 0.f;
    if (mode == 0) { int ky = tp / 3, kx = tp % 3; v = w[(size_t)(n * K + k) * 9 + ky * 3 + kx]; }
    else if (mode == 1) { v = w[(size_t)k * N + n]; }
    else if (mode == 2) { v = w[((size_t)tp * K + k) * N + n]; }
    else { if (k < 27) { int tap = k / 3, c = k % 3; int ky = tap / 3, kx = tap % 3;
                         v = w[((n * 3 + c) * 3 + ky) * 3 + kx]; } }
    dst[idx] = f2bf(v);
}

// ---------------- fused pad-ring zeroing (all buffers, one dispatch) --------
struct ZArgs { int off[10]; int cum[11]; int W2[10]; int H2[10]; int Cs[10]; };
__global__ __launch_bounds__(TPB) void k_zero_all(
    ZArgs za, unsigned short* __restrict__ W, int total)
{
    int idx = blockIdx.x * TPB + threadIdx.x;
    if (idx >= total) return;
    int e = 0;
    #pragma unroll
    for (int i = 1; i < 10; ++i) e += (idx >= za.cum[i]);
    int local = idx - za.cum[e];
    int W2 = za.W2[e], H2 = za.H2[e], Cs = za.Cs[e];
    int topbot = 2 * W2 * Cs;
    int iy, ix, c;
    if (local < topbot) {
        int row = local / (W2 * Cs); int rest = local - row * (W2 * Cs);
        iy = row ? (H2 - 1) : 0; ix = rest / Cs; c = rest - (rest / Cs) * Cs;
    } else {
        int idx2 = local - topbot;
        int per = (H2 - 2) * Cs;
        int side = idx2 / per; int rest = idx2 - side * per;
        iy = 1 + rest / Cs; ix = side ? (W2 - 1) : 0; c = rest - (rest / Cs) * Cs;
    }
    W[(size_t)za.off[e] + ((size_t)iy * W2 + ix) * Cs + c] = 0;
}

// ---------------- conv1 im2col: x fp32 [3][256][256] -> xcol bf16 [65536][32]
__global__ __launch_bounds__(TPB) void k_im2col(
    const float* __restrict__ x, unsigned short* __restrict__ xcol)
{
    int idx = blockIdx.x * TPB + threadIdx.x;
    if (idx >= 65536 * 32) return;
    int k = idx & 31, m = idx >> 5;
    int y = m >> 8, xx = m & 255;
    float v = 0.f;
    if (k < 27) {
        int tap = k / 3, c = k - tap * 3;
        int ty = tap / 3, tx = tap % 3;
        int yy = y + ty - 1, xp = xx + tx - 1;
        if (yy >= 0 && yy < 256 && xp >= 0 && xp < 256)
            v = x[c * 65536 + yy * 256 + xp];
    }
    xcol[idx] = f2bf(v);
}

// ---------------- maxpool 2x2 channels-last (strided in/out) ----------------
__global__ __launch_bounds__(TPB) void k_maxpool(
    const unsigned short* __restrict__ inI, unsigned short* __restrict__ outI,
    int Wo, int C4, int CsIn, int inPitch, int CsOut, int outPitch, int total)
{
    int idx = blockIdx.x * TPB + threadIdx.x;
    if (idx >= total) return;
    int c4 = idx % C4; int p = idx / C4;
    int x = p % Wo, y = p / Wo;
    const unsigned short* ip = inI + (size_t)(2 * y) * inPitch + (size_t)(2 * x) * CsIn + c4 * 4;
    ushort4 a = *(const ushort4*)(ip);
    ushort4 b = *(const ushort4*)(ip + CsIn);
    ushort4 c = *(const ushort4*)(ip + inPitch);
    ushort4 d = *(const ushort4*)(ip + inPitch + CsIn);
    ushort4 o;
    o.x = f2bf(fmaxf(fmaxf(bf2f(a.x), bf2f(b.x)), fmaxf(bf2f(c.x), bf2f(d.x))));
    o.y = f2bf(fmaxf(fmaxf(bf2f(a.y), bf2f(b.y)), fmaxf(bf2f(c.y), bf2f(d.y))));
    o.z = f2bf(fmaxf(fmaxf(bf2f(a.z), bf2f(b.z)), fmaxf(bf2f(c.z), bf2f(d.z))));
    o.w = f2bf(fmaxf(fmaxf(bf2f(a.w), bf2f(b.w)), fmaxf(bf2f(c.w), bf2f(d.w))));
    *(ushort4*)(outI + (size_t)y * outPitch + (size_t)x * CsOut + c4 * 4) = o;
}

// ---------------- graph aggregation on 66x66 grid, node-major bf16 ----------
__global__ __launch_bounds__(TPB) void k_gagg(
    const unsigned short* __restrict__ X, unsigned short* __restrict__ agg,
    int C, int total)
{
    int idx = blockIdx.x * TPB + threadIdx.x;
    if (idx >= total) return;
    int C4 = C >> 2;
    int c4 = idx % C4; int n = idx / C4;
    int i = n / 66, j = n - i * 66;
    size_t base = (size_t)n * C + c4 * 4;
    ushort4 s = *(const ushort4*)(X + base);
    float v0 = bf2f(s.x), v1 = bf2f(s.y), v2 = bf2f(s.z), v3 = bf2f(s.w);
    float cnt = 1.f;
    if (i > 0)  { ushort4 u = *(const ushort4*)(X + base - (size_t)66 * C);
                  v0 += bf2f(u.x); v1 += bf2f(u.y); v2 += bf2f(u.z); v3 += bf2f(u.w); cnt += 1.f; }
    if (i < 65) { ushort4 u = *(const ushort4*)(X + base + (size_t)66 * C);
                  v0 += bf2f(u.x); v1 += bf2f(u.y); v2 += bf2f(u.z); v3 += bf2f(u.w); cnt += 1.f; }
    if (j > 0)  { ushort4 u = *(const ushort4*)(X + base - C);
                  v0 += bf2f(u.x); v1 += bf2f(u.y); v2 += bf2f(u.z); v3 += bf2f(u.w); cnt += 1.f; }
    if (j < 65) { ushort4 u = *(const ushort4*)(X + base + C);
                  v0 += bf2f(u.x); v1 += bf2f(u.y); v2 += bf2f(u.z); v3 += bf2f(u.w); cnt += 1.f; }
    float inv = 1.f / cnt;
    ushort4 o;
    o.x = f2bf(v0 * inv); o.y = f2bf(v1 * inv); o.z = f2bf(v2 * inv); o.w = f2bf(v3 * inv);
    *(ushort4*)(agg + base) = o;
}

// ---------------- final conv 64->1, fp32 out --------------------------------
__global__ __launch_bounds__(TPB) void k_outconv(
    const unsigned short* __restrict__ vI, const float* __restrict__ ow,
    const float* __restrict__ ob, float* __restrict__ out)
{
    __shared__ float wl[576];
    for (int i = threadIdx.x; i < 576; i += TPB) wl[i] = ow[i];
    __syncthreads();
    int p = blockIdx.x * TPB + threadIdx.x;
    int y = p >> 8, x = p & 255;
    float acc = ob[0];
    #pragma unroll
    for (int ky = 0; ky < 3; ++ky)
        #pragma unroll
        for (int kx = 0; kx < 3; ++kx) {
            const unsigned short* ip = vI + (size_t)((y + ky - 1) * 258 + (x + kx - 1)) * 64;
            int wb = ky * 3 + kx;
            for (int c = 0; c < 64; c += 4) {
                ushort4 uv = *(const ushort4*)(ip + c);
                acc += bf2f(uv.x) * wl[c * 9 + wb] + bf2f(uv.y) * wl[(c + 1) * 9 + wb]
                     + bf2f(uv.z) * wl[(c + 2) * 9 + wb] + bf2f(uv.w) * wl[(c + 3) * 9 + wb];
            }
        }
    out[p] = acc;
}

static inline TapOffs zero_toffs() { TapOffs t = {}; return t; }

extern "C" void kernel_launch(void* const* d_in, const int* in_sizes, int n_in,
                              void* d_out, int out_size, void* d_ws, size_t ws_size,
                              hipStream_t stream) {
    const float* x    = (const float*)d_in[0];
    const float* d1w1 = (const float*)d_in[1];  const float* d1b1 = (const float*)d_in[2];
    const float* d1w2 = (const float*)d_in[3];  const float* d1b2 = (const float*)d_in[4];
    const float* d2w1 = (const float*)d_in[5];  const float* d2b1 = (const float*)d_in[6];
    const float* d2w2 = (const float*)d_in[7];  const float* d2b2 = (const float*)d_in[8];
    const float* md1w = (const float*)d_in[9];  const float* md1b = (const float*)d_in[10];
    const float* md2w = (const float*)d_in[11]; const float* md2b = (const float*)d_in[12];
    const float* mbw  = (const float*)d_in[13]; const float* mbb  = (const float*)d_in[14];
    const float* mu1w = (const float*)d_in[15]; const float* mu1b = (const float*)d_in[16];
    const float* mu2w = (const float*)d_in[17]; const float* mu2b = (const float*)d_in[18];
    const float* u3tw = (const float*)d_in[19]; const float* u3tb = (const float*)d_in[20];
    const float* u3w1 = (const float*)d_in[21]; const float* u3b1 = (const float*)d_in[22];
    const float* u3w2 = (const float*)d_in[23]; const float* u3b2 = (const float*)d_in[24];
    const float* u4tw = (const float*)d_in[25]; const float* u4tb = (const float*)d_in[26];
    const float* u4w1 = (const float*)d_in[27]; const float* u4b1 = (const float*)d_in[28];
    const float* u4w2 = (const float*)d_in[29]; const float* u4b2 = (const float*)d_in[30];
    const float* ow   = (const float*)d_in[31]; const float* ob   = (const float*)d_in[32];
    float* out = (float*)d_out;

    unsigned short* W = (unsigned short*)d_ws;

    // ---- flat arena (elem offsets, bf16) ----
    const size_t XCOL = 0;          // 2,097,152
    const size_t A1   = 2097152;    // 258*258*64
    const size_t CAT4 = 6357248;    // 258*258*128
    const size_t P1   = 14877440;   // 130*130*64
    const size_t T2   = 15959040;   // 130*130*128
    const size_t CAT3 = 18122240;   // 130*130*256
    const size_t X0   = 22448640;   // 66*66*128
    const size_t BP1  = 23006208;   // 4608*256
    const size_t BP2  = 24185856;   // 4608*512
    const size_t XB   = 26545152;   // 4608*1024
    const size_t XC   = 31263744;   // 4608*512
    const size_t XD   = 33623040;   // 4608*256
    const size_t V3A  = 34802688;   // 130*130*128
    const size_t V3B  = 36965888;   // 130*130*128
    const size_t V4A  = 39129088;   // 258*258*64
    const size_t V4B  = 43389184;   // 258*258*64
    const size_t AGG  = 47649280;   // 4608*1024
    const size_t WP   = 52367872;   // packed weights 2,320,384

    const size_t a1I   = A1 + 259 * 64;
    const size_t cat4I = CAT4 + 259 * 128;
    const size_t p1I   = P1 + 131 * 64;
    const size_t t2I   = T2 + 131 * 128;
    const size_t cat3I = CAT3 + 131 * 256;
    const size_t X0I   = X0 + 67 * 128;
    const size_t XdI   = XD + 67 * 256;
    const size_t v3aI  = V3A + 131 * 128;
    const size_t v3bI  = V3B + 131 * 128;
    const size_t v4aI  = V4A + 259 * 64;
    const size_t v4bI  = V4B + 259 * 64;

    dim3 blk(TPB);
    const int BIG = 1 << 28;

    // ---- fused pad-ring zeroing ----
    {
        ZArgs za;
        const int off[10] = {(int)A1,(int)CAT4,(int)P1,(int)T2,(int)CAT3,(int)V3A,(int)V3B,(int)V4A,(int)V4B,(int)X0};
        const int w2 [10] = {258,258,130,130,130,130,130,258,258,66};
        const int h2 [10] = {258,258,130,130,130,130,130,258,258,66};
        const int cs [10] = {64,128,64,128,256,128,128,64,64,128};
        int cum = 0;
        for (int i = 0; i < 10; ++i) {
            za.off[i]=off[i]; za.W2[i]=w2[i]; za.H2[i]=h2[i]; za.Cs[i]=cs[i];
            za.cum[i]=cum; cum += (w2[i]*h2[i] - (w2[i]-2)*(h2[i]-2))*cs[i];
        }
        za.cum[10]=cum;
        k_zero_all<<<dim3((cum + TPB - 1) / TPB), blk, 0, stream>>>(za, W, cum);
    }

    // ---- fused weight packing ----
    {
        PackArgs pa;
        const float* ws_[15] = {d1w1,d1w2,d2w1,d2w2,md1w,md2w,mbw,mu1w,mu2w,u3tw,u3w1,u3w2,u4tw,u4w1,u4w2};
        const int mode[15] = {3,0,0,0,1,1,1,1,1,2,0,0,2,0,0};
        const int kc [15] = {1,2,2,4,4,8,16,32,16,8,8,4,4,4,2};
        const int nt [15] = {4,4,8,8,16,32,64,32,16,8,8,8,4,4,4};
        const int kk [15] = {32,64,64,128,128,256,512,1024,512,256,256,128,128,128,64};
        const int nn [15] = {64,64,128,128,256,512,1024,512,256,128,128,128,64,64,64};
        const int tt [15] = {1,9,9,9,1,1,1,1,1,4,9,9,4,9,9};
        int cum = 0;
        for (int i = 0; i < 15; ++i) {
            pa.w[i]=ws_[i]; pa.mode[i]=mode[i]; pa.KC[i]=kc[i]; pa.NT[i]=nt[i];
            pa.K[i]=kk[i]; pa.N[i]=nn[i]; pa.cum[i]=cum;
            cum += tt[i]*kc[i]*nt[i]*512;
        }
        pa.cum[15]=cum;
        k_pack_all<<<dim3((cum + TPB - 1) / TPB), blk, 0, stream>>>(pa, W + WP, cum);
    }
    const size_t pw_d1w1=WP+0, pw_d1w2=WP+2048, pw_d2w1=WP+38912, pw_d2w2=WP+112640,
        pw_md1=WP+260096, pw_md2=WP+292864, pw_mb=WP+423936, pw_mu1=WP+948224,
        pw_mu2=WP+1472512, pw_u3t=WP+1603584, pw_u3w1=WP+1734656, pw_u3w2=WP+2029568,
        pw_u4t=WP+2177024, pw_u4w1=WP+2209792, pw_u4w2=WP+2283520;

    // ---- encoder ----
    k_im2col<<<dim3(8192), blk, 0, stream>>>(x, W + XCOL);
    k_gemm<2,1><<<dim3(512,1), blk, 0, stream>>>(W + XCOL, W + pw_d1w1, d1b1, nullptr, 0,
        W + a1I, 32, 8192, 256, 64, 258*64, 1, zero_toffs(), 4, 1, 0,0,0);
    k_conv3<1><<<dim3(256,1), blk, 0, stream>>>(W + a1I, W + pw_d1w2, d1b2,
        W + cat4I, 258*64, 4, 128, 258*128, 4);
    k_maxpool<<<dim3(1024), blk, 0, stream>>>(W + cat4I, W + p1I, 128, 16, 128, 258*128, 64, 130*64, 128*128*16);
    k_conv3<1><<<dim3(64,2), blk, 0, stream>>>(W + p1I, W + pw_d2w1, d2b1,
        W + t2I, 130*64, 2, 128, 130*128, 8);
    k_conv3<2><<<dim3(64,4), blk, 0, stream>>>(W + t2I, W + pw_d2w2, d2b2,
        W + cat3I, 130*128, 2, 256, 130*256, 8);
    k_maxpool<<<dim3(512), blk, 0, stream>>>(W + cat3I, W + X0I, 64, 32, 256, 130*256, 128, 66*128, 64*64*32);

    // ---- GNN on 66x66 padded grid ----
    k_gagg<<<dim3(545), blk, 0, stream>>>(W + X0, W + AGG, 128, 4356*32);
    k_gemm<4,4><<<dim3(18,4), blk, 0, stream>>>(W + AGG, W + pw_md1, md1b, nullptr, 0,
        W + BP1, 128, 0, BIG, 256, 0, 1, zero_toffs(), 16, 1, 0,0,0);
    k_gagg<<<dim3(1089), blk, 0, stream>>>(W + BP1, W + AGG, 256, 4356*64);
    k_gemm<4,8><<<dim3(18,8), blk, 0, stream>>>(W + AGG, W + pw_md2, md2b, nullptr, 0,
        W + BP2, 256, 0, BIG, 512, 0, 1, zero_toffs(), 32, 1, 0,0,0);
    k_gagg<<<dim3(2178), blk, 0, stream>>>(W + BP2, W + AGG, 512, 4356*128);
    k_gemm<4,16><<<dim3(18,16), blk, 0, stream>>>(W + AGG, W + pw_mb, mbb, nullptr, 0,
        W + XB, 512, 0, BIG, 1024, 0, 1, zero_toffs(), 64, 1, 0,0,0);
    k_gagg<<<dim3(4356), blk, 0, stream>>>(W + XB, W + AGG, 1024, 4356*256);
    k_gemm<4,32><<<dim3(18,8), blk, 0, stream>>>(W + AGG, W + pw_mu1, mu1b, W + BP2, 512,
        W + XC, 1024, 0, BIG, 512, 0, 1, zero_toffs(), 32, 1, 0,0,0);
    k_gagg<<<dim3(2178), blk, 0, stream>>>(W + XC, W + AGG, 512, 4356*128);
    k_gemm<4,16><<<dim3(18,4), blk, 0, stream>>>(W + AGG, W + pw_mu2, mu2b, W + BP1, 256,
        W + XD, 512, 0, BIG, 256, 0, 1, zero_toffs(), 16, 1, 0,0,0);

    // ---- decoder stage 3 ----
    k_gemm<2,8><<<dim3(32,2,4), blk, 0, stream>>>(W + XdI, W + pw_u3t, u3tb, nullptr, 0,
        W + cat3I + 128, 256, 66*256, 64, 512, 2*130*256, 1, zero_toffs(), 8, 0, 1, 130*256, 256);
    k_conv3<4><<<dim3(64,2), blk, 0, stream>>>(W + cat3I, W + pw_u3w1, u3b1,
        W + v3aI, 130*256, 2, 128, 130*128, 8);
    k_conv3<2><<<dim3(64,2), blk, 0, stream>>>(W + v3aI, W + pw_u3w2, u3b2,
        W + v3bI, 130*128, 2, 128, 130*128, 8);

    // ---- decoder stage 4 ----
    k_gemm<2,4><<<dim3(128,1,4), blk, 0, stream>>>(W + v3bI, W + pw_u4t, u4tb, nullptr, 0,
        W + cat4I + 64, 128, 130*128, 128, 256, 2*258*128, 1, zero_toffs(), 4, 0, 1, 258*128, 128);
    k_conv3<2><<<dim3(256,1), blk, 0, stream>>>(W + cat4I, W + pw_u4w1, u4b1,
        W + v4aI, 258*128, 4, 64, 258*64, 4);
    k_conv3<1><<<dim3(256,1), blk, 0, stream>>>(W + v4aI, W + pw_u4w2, u4b2,
        W + v4bI, 258*64, 4, 64, 258*64, 4);

    // ---- output conv 64->1, fp32 ----
    k_outconv<<<dim3(256), blk, 0, stream>>>(W + v4bI, ow, ob, out);
}

// Round 5
// 490.238 us; speedup vs baseline: 1.0483x; 1.0483x over previous
//
#include <hip/hip_runtime.h>
#include <cstddef>

#define TPB 256

typedef __attribute__((ext_vector_type(8))) short short8;
typedef __attribute__((ext_vector_type(4))) float f32x4;

__device__ inline unsigned short f2bf(float f) {
    unsigned int u = __builtin_bit_cast(unsigned int, f);
    u += 0x7fffu + ((u >> 16) & 1u);
    return (unsigned short)(u >> 16);
}
__device__ inline float bf2f(unsigned short h) {
    unsigned int u = ((unsigned int)h) << 16;
    return __builtin_bit_cast(float, u);
}

struct TapOffs { int o[9]; };

// ---------------------------------------------------------------------------
// 3x3 conv GEMM: A direct from global (channels-last, L1-cached 9x tap reuse),
// B staged in LDS (fragment order, lane*16B linear reads = conflict-free),
// double-buffered by 3-tap (ky) groups. Block = 64px x 2 rows, TPB=128
// (2 waves, wave = one pixel row). Per wave: MW=4 m-frags x NT=4 n-frags =
// 16 MFMA per 4 global A-loads + 4 LDS B-reads; 96 MFMAs between barriers.
// LDS = 2 x 24 KB -> 3 blocks/CU cap.
// mfma_f32_16x16x32_bf16: A[m=lane&15][k=(lane>>4)*8+j], B[k][n=lane&15],
// D: col(n)=lane&15, row(m)=(lane>>4)*4+reg.
// ---------------------------------------------------------------------------
template<int CHUNKS>   // input channels = CHUNKS*64
__global__ __launch_bounds__(128) void k_conv3g(
    const unsigned short* __restrict__ A0, const unsigned short* __restrict__ Wf,
    const float* __restrict__ bias, unsigned short* __restrict__ O0,
    int AP, int tilesX, int OMS, int OP, int NTtot)
{
    constexpr int Cs  = CHUNKS * 64;
    constexpr int KC2 = CHUNKS * 2;          // k32-steps per tap (whole K)
    __shared__ unsigned short Bs[2][12288];  // 2 x 24,576 B

    int lane = threadIdx.x & 63, wave = threadIdx.x >> 6;   // wave 0..1
    int ml = lane & 15, kq = lane >> 4;
    int nb = blockIdx.y;
    int tileX = blockIdx.x % tilesX, tileY = blockIdx.x / tilesX;
    int gx0 = tileX * 64, gy = tileY * 2 + wave;

    // per-lane A base at (row gy-1, px gx0+ml-1), k-chunk kq
    const unsigned short* Abase = A0 + (size_t)(gy - 1) * AP
                                     + (size_t)(gx0 + ml - 1) * Cs + kq * 8;

    f32x4 acc[4][4];
    #pragma unroll
    for (int mf = 0; mf < 4; ++mf)
        #pragma unroll
        for (int nt = 0; nt < 4; ++nt) acc[mf][nt] = (f32x4){0.f, 0.f, 0.f, 0.f};

    const int G = CHUNKS * 3;   // groups: (chunk, ky)

    // ---- stage group g's B (3 kx-taps x 2q x 4nt x 512) into Bs[g&1] ----
    auto stageB = [&](int g) {
        int ch = g / 3, ky = g - (g / 3) * 3;
        unsigned short* bd = Bs[g & 1];
        #pragma unroll
        for (int it = 0; it < 12; ++it) {
            int u = threadIdx.x + it * 128;     // 1536 int4 loads total
            int e = u * 8;
            int kxq = e >> 11;                  // [kx*2+q] 0..5
            int rem = e & 2047;                 // nt*512 + r
            int kx = kxq >> 1, q = kxq & 1;
            const unsigned short* src = Wf
                + ((size_t)((ky * 3 + kx) * KC2 + ch * 2 + q) * NTtot + nb * 4) * 512 + rem;
            *(int4*)&bd[e] = *(const int4*)src;
        }
    };

    stageB(0);
    __syncthreads();
    for (int g = 0; g < G; ++g) {
        if (g + 1 < G) stageB(g + 1);
        int ch = g / 3, ky = g - (g / 3) * 3;
        const unsigned short* Ar = Abase + (size_t)ky * AP + ch * 64;
        const unsigned short* Bb = &Bs[g & 1][lane * 8];
        #pragma unroll
        for (int kx = 0; kx < 3; ++kx) {
            #pragma unroll
            for (int q = 0; q < 2; ++q) {
                short8 b[4];
                #pragma unroll
                for (int nt = 0; nt < 4; ++nt)
                    b[nt] = *(const short8*)(Bb + (kx * 2 + q) * 2048 + nt * 512);
                short8 a[4];
                #pragma unroll
                for (int mf = 0; mf < 4; ++mf)
                    a[mf] = *(const short8*)(Ar + (size_t)(kx + mf * 16) * Cs + q * 32);
                #pragma unroll
                for (int mf = 0; mf < 4; ++mf)
                    #pragma unroll
                    for (int nt = 0; nt < 4; ++nt)
                        acc[mf][nt] = __builtin_amdgcn_mfma_f32_16x16x32_bf16(a[mf], b[nt], acc[mf][nt], 0, 0, 0);
            }
        }
        __syncthreads();
    }

    // ---- epilogue: bias + relu, channels-last stores ----
    unsigned short* Orow = O0 + (size_t)gy * OP + (size_t)nb * 64;
    #pragma unroll
    for (int mf = 0; mf < 4; ++mf) {
        int gx = gx0 + mf * 16 + kq * 4;
        #pragma unroll
        for (int nt = 0; nt < 4; ++nt) {
            float bv = bias[nb * 64 + nt * 16 + ml];
            #pragma unroll
            for (int r = 0; r < 4; ++r) {
                float v = fmaxf(acc[mf][nt][r] + bv, 0.f);
                Orow[(size_t)(gx + r) * OMS + nt * 16 + ml] = f2bf(v);
            }
        }
    }
}

// ---------------------------------------------------------------------------
// Generic MFMA GEMM (global-direct), MW m-frags per wave. Used for conv1,
// convT (ct=1: blockIdx.z = tap, parity-shifted output) and GNN matmuls.
// ---------------------------------------------------------------------------
template<int MW, int KC>
__global__ __launch_bounds__(TPB) void k_gemm(
    const unsigned short* __restrict__ A0, const unsigned short* __restrict__ Wf,
    const float* __restrict__ bias, const unsigned short* __restrict__ resid, int RS,
    unsigned short* __restrict__ O0,
    int Cs, int AP, int Wimg, int OMS, int OP,
    int T, TapOffs toffs, int NTtot, int relu, int ct, int ctDy, int ctDx)
{
    int lane = threadIdx.x & 63, wave = threadIdx.x >> 6;
    int ml = lane & 15, kq = lane >> 4;
    int nb = blockIdx.y;

    const unsigned short* Wb = Wf;
    unsigned short* Ob = O0;
    if (ct) {
        int tp = blockIdx.z;
        Wb += (size_t)(tp * KC) * NTtot * 512;
        int dy = 1 - (tp >> 1), dx = 1 - (tp & 1);   // jax conv_transpose tap flip
        Ob += (size_t)dy * ctDy + (size_t)dx * ctDx;
    }
    const unsigned short* WbB = Wb + (size_t)(nb * 4) * 512 + lane * 8;

    int fy[MW], fx[MW];
    const unsigned short* Af[MW];
    #pragma unroll
    for (int f = 0; f < MW; ++f) {
        int mf = (blockIdx.x * 4 + wave) * (16 * MW) + f * 16;
        int y = mf / Wimg, x = mf - y * Wimg;
        fy[f] = y; fx[f] = x;
        Af[f] = A0 + (size_t)y * AP + (size_t)(x + ml) * Cs + kq * 8;
    }

    f32x4 acc[MW][4];
    #pragma unroll
    for (int f = 0; f < MW; ++f)
        #pragma unroll
        for (int nt = 0; nt < 4; ++nt) acc[f][nt] = (f32x4){0.f, 0.f, 0.f, 0.f};

    for (int tp = 0; tp < T; ++tp) {
        int toff = toffs.o[tp];
        const unsigned short* Wt = WbB + (size_t)(tp * KC) * NTtot * 512;
        #pragma unroll
        for (int q = 0; q < KC; ++q) {
            short8 b[4];
            #pragma unroll
            for (int nt = 0; nt < 4; ++nt)
                b[nt] = *(const short8*)(Wt + (size_t)q * NTtot * 512 + nt * 512);
            short8 a[MW];
            #pragma unroll
            for (int f = 0; f < MW; ++f)
                a[f] = *(const short8*)(Af[f] + toff + q * 32);
            #pragma unroll
            for (int f = 0; f < MW; ++f)
                #pragma unroll
                for (int nt = 0; nt < 4; ++nt)
                    acc[f][nt] = __builtin_amdgcn_mfma_f32_16x16x32_bf16(a[f], b[nt], acc[f][nt], 0, 0, 0);
        }
    }

    #pragma unroll
    for (int f = 0; f < MW; ++f) {
        unsigned short* Ot = Ob + (size_t)fy[f] * OP + (size_t)(fx[f] + kq * 4) * OMS + (size_t)nb * 64;
        int mg0 = (blockIdx.x * 4 + wave) * (16 * MW) + f * 16 + kq * 4;
        #pragma unroll
        for (int nt = 0; nt < 4; ++nt) {
            int ng = nb * 64 + nt * 16 + ml;
            float bv = bias[ng];
            #pragma unroll
            for (int r = 0; r < 4; ++r) {
                float v = acc[f][nt][r] + bv;
                if (relu) v = fmaxf(v, 0.f);
                if (resid) v += bf2f(resid[(size_t)(mg0 + r) * RS + ng]);
                Ot[(size_t)r * OMS + nt * 16 + ml] = f2bf(v);
            }
        }
    }
}

// ---------------- fused weight packing (all 15 tensors, one dispatch) -------
struct PackArgs {
    const float* w[15];
    int cum[16];
    int mode[15], KC[15], NT[15], K[15], N[15];
};
__global__ __launch_bounds__(TPB) void k_pack_all(
    PackArgs pa, unsigned short* __restrict__ dst, int total)
{
    int idx = blockIdx.x * TPB + threadIdx.x;
    if (idx >= total) return;
    int e = 0;
    #pragma unroll
    for (int i = 1; i < 15; ++i) e += (idx >= pa.cum[i]);
    int local = idx - pa.cum[e];
    const float* w = pa.w[e];
    int KC = pa.KC[e], NT = pa.NT[e], K = pa.K[e], N = pa.N[e], mode = pa.mode[e];

    int j = local & 7, l = (local >> 3) & 63;
    int r = local >> 9;
    int ntg = r % NT; int r2 = r / NT;
    int q = r2 % KC; int tp = r2 / KC;
    int k = q * 32 + (l >> 4) * 8 + j;
    int n = ntg * 16 + (l & 15);
    float v = 0.f;
    if (mode == 0) { int ky = tp / 3, kx = tp % 3; v = w[(size_t)(n * K + k) * 9 + ky * 3 + kx]; }
    else if (mode == 1) { v = w[(size_t)k * N + n]; }
    else if (mode == 2) { v = w[((size_t)tp * K + k) * N + n]; }
    else { if (k < 27) { int tap = k / 3, c = k % 3; int ky = tap / 3, kx = tap % 3;
                         v = w[((n * 3 + c) * 3 + ky) * 3 + kx]; } }
    dst[idx] = f2bf(v);
}

// ---------------- fused pad-ring zeroing (all buffers, one dispatch) --------
struct ZArgs { int off[10]; int cum[11]; int W2[10]; int H2[10]; int Cs[10]; };
__global__ __launch_bounds__(TPB) void k_zero_all(
    ZArgs za, unsigned short* __restrict__ W, int total)
{
    int idx = blockIdx.x * TPB + threadIdx.x;
    if (idx >= total) return;
    int e = 0;
    #pragma unroll
    for (int i = 1; i < 10; ++i) e += (idx >= za.cum[i]);
    int local = idx - za.cum[e];
    int W2 = za.W2[e], H2 = za.H2[e], Cs = za.Cs[e];
    int topbot = 2 * W2 * Cs;
    int iy, ix, c;
    if (local < topbot) {
        int row = local / (W2 * Cs); int rest = local - row * (W2 * Cs);
        iy = row ? (H2 - 1) : 0; ix = rest / Cs; c = rest - (rest / Cs) * Cs;
    } else {
        int idx2 = local - topbot;
        int per = (H2 - 2) * Cs;
        int side = idx2 / per; int rest = idx2 - side * per;
        iy = 1 + rest / Cs; ix = side ? (W2 - 1) : 0; c = rest - (rest / Cs) * Cs;
    }
    W[(size_t)za.off[e] + ((size_t)iy * W2 + ix) * Cs + c] = 0;
}

// ---------------- conv1 im2col: x fp32 [3][256][256] -> xcol bf16 [65536][32]
__global__ __launch_bounds__(TPB) void k_im2col(
    const float* __restrict__ x, unsigned short* __restrict__ xcol)
{
    int idx = blockIdx.x * TPB + threadIdx.x;
    if (idx >= 65536 * 32) return;
    int k = idx & 31, m = idx >> 5;
    int y = m >> 8, xx = m & 255;
    float v = 0.f;
    if (k < 27) {
        int tap = k / 3, c = k - tap * 3;
        int ty = tap / 3, tx = tap % 3;
        int yy = y + ty - 1, xp = xx + tx - 1;
        if (yy >= 0 && yy < 256 && xp >= 0 && xp < 256)
            v = x[c * 65536 + yy * 256 + xp];
    }
    xcol[idx] = f2bf(v);
}

// ---------------- maxpool 2x2 channels-last (strided in/out) ----------------
__global__ __launch_bounds__(TPB) void k_maxpool(
    const unsigned short* __restrict__ inI, unsigned short* __restrict__ outI,
    int Wo, int C4, int CsIn, int inPitch, int CsOut, int outPitch, int total)
{
    int idx = blockIdx.x * TPB + threadIdx.x;
    if (idx >= total) return;
    int c4 = idx % C4; int p = idx / C4;
    int x = p % Wo, y = p / Wo;
    const unsigned short* ip = inI + (size_t)(2 * y) * inPitch + (size_t)(2 * x) * CsIn + c4 * 4;
    ushort4 a = *(const ushort4*)(ip);
    ushort4 b = *(const ushort4*)(ip + CsIn);
    ushort4 c = *(const ushort4*)(ip + inPitch);
    ushort4 d = *(const ushort4*)(ip + inPitch + CsIn);
    ushort4 o;
    o.x = f2bf(fmaxf(fmaxf(bf2f(a.x), bf2f(b.x)), fmaxf(bf2f(c.x), bf2f(d.x))));
    o.y = f2bf(fmaxf(fmaxf(bf2f(a.y), bf2f(b.y)), fmaxf(bf2f(c.y), bf2f(d.y))));
    o.z = f2bf(fmaxf(fmaxf(bf2f(a.z), bf2f(b.z)), fmaxf(bf2f(c.z), bf2f(d.z))));
    o.w = f2bf(fmaxf(fmaxf(bf2f(a.w), bf2f(b.w)), fmaxf(bf2f(c.w), bf2f(d.w))));
    *(ushort4*)(outI + (size_t)y * outPitch + (size_t)x * CsOut + c4 * 4) = o;
}

// ---------------- graph aggregation on 66x66 grid, node-major bf16 ----------
__global__ __launch_bounds__(TPB) void k_gagg(
    const unsigned short* __restrict__ X, unsigned short* __restrict__ agg,
    int C, int total)
{
    int idx = blockIdx.x * TPB + threadIdx.x;
    if (idx >= total) return;
    int C4 = C >> 2;
    int c4 = idx % C4; int n = idx / C4;
    int i = n / 66, j = n - i * 66;
    size_t base = (size_t)n * C + c4 * 4;
    ushort4 s = *(const ushort4*)(X + base);
    float v0 = bf2f(s.x), v1 = bf2f(s.y), v2 = bf2f(s.z), v3 = bf2f(s.w);
    float cnt = 1.f;
    if (i > 0)  { ushort4 u = *(const ushort4*)(X + base - (size_t)66 * C);
                  v0 += bf2f(u.x); v1 += bf2f(u.y); v2 += bf2f(u.z); v3 += bf2f(u.w); cnt += 1.f; }
    if (i < 65) { ushort4 u = *(const ushort4*)(X + base + (size_t)66 * C);
                  v0 += bf2f(u.x); v1 += bf2f(u.y); v2 += bf2f(u.z); v3 += bf2f(u.w); cnt += 1.f; }
    if (j > 0)  { ushort4 u = *(const ushort4*)(X + base - C);
                  v0 += bf2f(u.x); v1 += bf2f(u.y); v2 += bf2f(u.z); v3 += bf2f(u.w); cnt += 1.f; }
    if (j < 65) { ushort4 u = *(const ushort4*)(X + base + C);
                  v0 += bf2f(u.x); v1 += bf2f(u.y); v2 += bf2f(u.z); v3 += bf2f(u.w); cnt += 1.f; }
    float inv = 1.f / cnt;
    ushort4 o;
    o.x = f2bf(v0 * inv); o.y = f2bf(v1 * inv); o.z = f2bf(v2 * inv); o.w = f2bf(v3 * inv);
    *(ushort4*)(agg + base) = o;
}

// ---------------- final conv 64->1, fp32 out --------------------------------
__global__ __launch_bounds__(TPB) void k_outconv(
    const unsigned short* __restrict__ vI, const float* __restrict__ ow,
    const float* __restrict__ ob, float* __restrict__ out)
{
    __shared__ float wl[576];
    for (int i = threadIdx.x; i < 576; i += TPB) wl[i] = ow[i];
    __syncthreads();
    int p = blockIdx.x * TPB + threadIdx.x;
    int y = p >> 8, x = p & 255;
    float acc = ob[0];
    #pragma unroll
    for (int ky = 0; ky < 3; ++ky)
        #pragma unroll
        for (int kx = 0; kx < 3; ++kx) {
            const unsigned short* ip = vI + (size_t)((y + ky - 1) * 258 + (x + kx - 1)) * 64;
            int wb = ky * 3 + kx;
            for (int c = 0; c < 64; c += 4) {
                ushort4 uv = *(const ushort4*)(ip + c);
                acc += bf2f(uv.x) * wl[c * 9 + wb] + bf2f(uv.y) * wl[(c + 1) * 9 + wb]
                     + bf2f(uv.z) * wl[(c + 2) * 9 + wb] + bf2f(uv.w) * wl[(c + 3) * 9 + wb];
            }
        }
    out[p] = acc;
}

static inline TapOffs zero_toffs() { TapOffs t = {}; return t; }

extern "C" void kernel_launch(void* const* d_in, const int* in_sizes, int n_in,
                              void* d_out, int out_size, void* d_ws, size_t ws_size,
                              hipStream_t stream) {
    const float* x    = (const float*)d_in[0];
    const float* d1w1 = (const float*)d_in[1];  const float* d1b1 = (const float*)d_in[2];
    const float* d1w2 = (const float*)d_in[3];  const float* d1b2 = (const float*)d_in[4];
    const float* d2w1 = (const float*)d_in[5];  const float* d2b1 = (const float*)d_in[6];
    const float* d2w2 = (const float*)d_in[7];  const float* d2b2 = (const float*)d_in[8];
    const float* md1w = (const float*)d_in[9];  const float* md1b = (const float*)d_in[10];
    const float* md2w = (const float*)d_in[11]; const float* md2b = (const float*)d_in[12];
    const float* mbw  = (const float*)d_in[13]; const float* mbb  = (const float*)d_in[14];
    const float* mu1w = (const float*)d_in[15]; const float* mu1b = (const float*)d_in[16];
    const float* mu2w = (const float*)d_in[17]; const float* mu2b = (const float*)d_in[18];
    const float* u3tw = (const float*)d_in[19]; const float* u3tb = (const float*)d_in[20];
    const float* u3w1 = (const float*)d_in[21]; const float* u3b1 = (const float*)d_in[22];
    const float* u3w2 = (const float*)d_in[23]; const float* u3b2 = (const float*)d_in[24];
    const float* u4tw = (const float*)d_in[25]; const float* u4tb = (const float*)d_in[26];
    const float* u4w1 = (const float*)d_in[27]; const float* u4b1 = (const float*)d_in[28];
    const float* u4w2 = (const float*)d_in[29]; const float* u4b2 = (const float*)d_in[30];
    const float* ow   = (const float*)d_in[31]; const float* ob   = (const float*)d_in[32];
    float* out = (float*)d_out;

    unsigned short* W = (unsigned short*)d_ws;

    // ---- flat arena (elem offsets, bf16) ----
    const size_t XCOL = 0;          // 2,097,152
    const size_t A1   = 2097152;    // 258*258*64
    const size_t CAT4 = 6357248;    // 258*258*128
    const size_t P1   = 14877440;   // 130*130*64
    const size_t T2   = 15959040;   // 130*130*128
    const size_t CAT3 = 18122240;   // 130*130*256
    const size_t X0   = 22448640;   // 66*66*128
    const size_t BP1  = 23006208;   // 4608*256
    const size_t BP2  = 24185856;   // 4608*512
    const size_t XB   = 26545152;   // 4608*1024
    const size_t XC   = 31263744;   // 4608*512
    const size_t XD   = 33623040;   // 4608*256
    const size_t V3A  = 34802688;   // 130*130*128
    const size_t V3B  = 36965888;   // 130*130*128
    const size_t V4A  = 39129088;   // 258*258*64
    const size_t V4B  = 43389184;   // 258*258*64
    const size_t AGG  = 47649280;   // 4608*1024
    const size_t WP   = 52367872;   // packed weights 2,320,384

    const size_t a1I   = A1 + 259 * 64;
    const size_t cat4I = CAT4 + 259 * 128;
    const size_t p1I   = P1 + 131 * 64;
    const size_t t2I   = T2 + 131 * 128;
    const size_t cat3I = CAT3 + 131 * 256;
    const size_t X0I   = X0 + 67 * 128;
    const size_t XdI   = XD + 67 * 256;
    const size_t v3aI  = V3A + 131 * 128;
    const size_t v3bI  = V3B + 131 * 128;
    const size_t v4aI  = V4A + 259 * 64;
    const size_t v4bI  = V4B + 259 * 64;

    dim3 blk(TPB), blk2(128);
    const int BIG = 1 << 28;

    // ---- fused pad-ring zeroing ----
    {
        ZArgs za;
        const int off[10] = {(int)A1,(int)CAT4,(int)P1,(int)T2,(int)CAT3,(int)V3A,(int)V3B,(int)V4A,(int)V4B,(int)X0};
        const int w2 [10] = {258,258,130,130,130,130,130,258,258,66};
        const int h2 [10] = {258,258,130,130,130,130,130,258,258,66};
        const int cs [10] = {64,128,64,128,256,128,128,64,64,128};
        int cum = 0;
        for (int i = 0; i < 10; ++i) {
            za.off[i]=off[i]; za.W2[i]=w2[i]; za.H2[i]=h2[i]; za.Cs[i]=cs[i];
            za.cum[i]=cum; cum += (w2[i]*h2[i] - (w2[i]-2)*(h2[i]-2))*cs[i];
        }
        za.cum[10]=cum;
        k_zero_all<<<dim3((cum + TPB - 1) / TPB), blk, 0, stream>>>(za, W, cum);
    }

    // ---- fused weight packing ----
    {
        PackArgs pa;
        const float* ws_[15] = {d1w1,d1w2,d2w1,d2w2,md1w,md2w,mbw,mu1w,mu2w,u3tw,u3w1,u3w2,u4tw,u4w1,u4w2};
        const int mode[15] = {3,0,0,0,1,1,1,1,1,2,0,0,2,0,0};
        const int kc [15] = {1,2,2,4,4,8,16,32,16,8,8,4,4,4,2};
        const int nt [15] = {4,4,8,8,16,32,64,32,16,8,8,8,4,4,4};
        const int kk [15] = {32,64,64,128,128,256,512,1024,512,256,256,128,128,128,64};
        const int nn [15] = {64,64,128,128,256,512,1024,512,256,128,128,128,64,64,64};
        const int tt [15] = {1,9,9,9,1,1,1,1,1,4,9,9,4,9,9};
        int cum = 0;
        for (int i = 0; i < 15; ++i) {
            pa.w[i]=ws_[i]; pa.mode[i]=mode[i]; pa.KC[i]=kc[i]; pa.NT[i]=nt[i];
            pa.K[i]=kk[i]; pa.N[i]=nn[i]; pa.cum[i]=cum;
            cum += tt[i]*kc[i]*nt[i]*512;
        }
        pa.cum[15]=cum;
        k_pack_all<<<dim3((cum + TPB - 1) / TPB), blk, 0, stream>>>(pa, W + WP, cum);
    }
    const size_t pw_d1w1=WP+0, pw_d1w2=WP+2048, pw_d2w1=WP+38912, pw_d2w2=WP+112640,
        pw_md1=WP+260096, pw_md2=WP+292864, pw_mb=WP+423936, pw_mu1=WP+948224,
        pw_mu2=WP+1472512, pw_u3t=WP+1603584, pw_u3w1=WP+1734656, pw_u3w2=WP+2029568,
        pw_u4t=WP+2177024, pw_u4w1=WP+2209792, pw_u4w2=WP+2283520;

    // ---- encoder ----
    k_im2col<<<dim3(8192), blk, 0, stream>>>(x, W + XCOL);
    k_gemm<2,1><<<dim3(512,1), blk, 0, stream>>>(W + XCOL, W + pw_d1w1, d1b1, nullptr, 0,
        W + a1I, 32, 8192, 256, 64, 258*64, 1, zero_toffs(), 4, 1, 0,0,0);
    k_conv3g<1><<<dim3(512,1), blk2, 0, stream>>>(W + a1I, W + pw_d1w2, d1b2,
        W + cat4I, 258*64, 4, 128, 258*128, 4);
    k_maxpool<<<dim3(1024), blk, 0, stream>>>(W + cat4I, W + p1I, 128, 16, 128, 258*128, 64, 130*64, 128*128*16);
    k_conv3g<1><<<dim3(128,2), blk2, 0, stream>>>(W + p1I, W + pw_d2w1, d2b1,
        W + t2I, 130*64, 2, 128, 130*128, 8);
    k_conv3g<2><<<dim3(128,2), blk2, 0, stream>>>(W + t2I, W + pw_d2w2, d2b2,
        W + cat3I, 130*128, 2, 256, 130*256, 8);
    k_maxpool<<<dim3(512), blk, 0, stream>>>(W + cat3I, W + X0I, 64, 32, 256, 130*256, 128, 66*128, 64*64*32);

    // ---- GNN on 66x66 padded grid ----
    k_gagg<<<dim3(545), blk, 0, stream>>>(W + X0, W + AGG, 128, 4356*32);
    k_gemm<4,4><<<dim3(18,4), blk, 0, stream>>>(W + AGG, W + pw_md1, md1b, nullptr, 0,
        W + BP1, 128, 0, BIG, 256, 0, 1, zero_toffs(), 16, 1, 0,0,0);
    k_gagg<<<dim3(1089), blk, 0, stream>>>(W + BP1, W + AGG, 256, 4356*64);
    k_gemm<4,8><<<dim3(18,8), blk, 0, stream>>>(W + AGG, W + pw_md2, md2b, nullptr, 0,
        W + BP2, 256, 0, BIG, 512, 0, 1, zero_toffs(), 32, 1, 0,0,0);
    k_gagg<<<dim3(2178), blk, 0, stream>>>(W + BP2, W + AGG, 512, 4356*128);
    k_gemm<4,16><<<dim3(18,16), blk, 0, stream>>>(W + AGG, W + pw_mb, mbb, nullptr, 0,
        W + XB, 512, 0, BIG, 1024, 0, 1, zero_toffs(), 64, 1, 0,0,0);
    k_gagg<<<dim3(4356), blk, 0, stream>>>(W + XB, W + AGG, 1024, 4356*256);
    k_gemm<4,32><<<dim3(18,8), blk, 0, stream>>>(W + AGG, W + pw_mu1, mu1b, W + BP2, 512,
        W + XC, 1024, 0, BIG, 512, 0, 1, zero_toffs(), 32, 1, 0,0,0);
    k_gagg<<<dim3(2178), blk, 0, stream>>>(W + XC, W + AGG, 512, 4356*128);
    k_gemm<4,16><<<dim3(18,4), blk, 0, stream>>>(W + AGG, W + pw_mu2, mu2b, W + BP1, 256,
        W + XD, 512, 0, BIG, 256, 0, 1, zero_toffs(), 16, 1, 0,0,0);

    // ---- decoder stage 3 ----
    k_gemm<2,8><<<dim3(32,2,4), blk, 0, stream>>>(W + XdI, W + pw_u3t, u3tb, nullptr, 0,
        W + cat3I + 128, 256, 66*256, 64, 512, 2*130*256, 1, zero_toffs(), 8, 0, 1, 130*256, 256);
    k_conv3g<4><<<dim3(128,2), blk2, 0, stream>>>(W + cat3I, W + pw_u3w1, u3b1,
        W + v3aI, 130*256, 2, 128, 130*128, 8);
    k_conv3g<2><<<dim3(128,2), blk2, 0, stream>>>(W + v3aI, W + pw_u3w2, u3b2,
        W + v3bI, 130*128, 2, 128, 130*128, 8);

    // ---- decoder stage 4 ----
    k_gemm<2,4><<<dim3(128,1,4), blk, 0, stream>>>(W + v3bI, W + pw_u4t, u4tb, nullptr, 0,
        W + cat4I + 64, 128, 130*128, 128, 256, 2*258*128, 1, zero_toffs(), 4, 0, 1, 258*128, 128);
    k_conv3g<2><<<dim3(512,1), blk2, 0, stream>>>(W + cat4I, W + pw_u4w1, u4b1,
        W + v4aI, 258*128, 4, 64, 258*64, 4);
    k_conv3g<1><<<dim3(512,1), blk2, 0, stream>>>(W + v4aI, W + pw_u4w2, u4b2,
        W + v4bI, 258*64, 4, 64, 258*64, 4);

    // ---- output conv 64->1, fp32 ----
    k_outconv<<<dim3(256), blk, 0, stream>>>(W + v4bI, ow, ob, out);
}

// Round 6
// 445.637 us; speedup vs baseline: 1.1533x; 1.1001x over previous
//
#include <hip/hip_runtime.h>
#include <cstddef>

#define TPB 256

typedef __attribute__((ext_vector_type(8))) short short8;
typedef __attribute__((ext_vector_type(4))) float f32x4;

__device__ inline unsigned short f2bf(float f) {
    unsigned int u = __builtin_bit_cast(unsigned int, f);
    u += 0x7fffu + ((u >> 16) & 1u);
    return (unsigned short)(u >> 16);
}
__device__ inline float bf2f(unsigned short h) {
    unsigned int u = ((unsigned int)h) << 16;
    return __builtin_bit_cast(float, u);
}

struct TapOffs { int o[9]; };

// ---------------------------------------------------------------------------
// K-split GNN GEMM: block = 64m x 64n tile, 4 waves each compute K/4, then
// LDS cross-wave reduce. Wave w computes m-frags in rotated order
// mf=(w+i)&3 so its own slice is acc[0] (no dynamic reg indexing).
// 12 LDS slots (3 foreign slices x 4 waves) = 48 KB -> 3 blocks/CU.
// A: node-major [M][K]; Wf: fragment-packed; O/resid: [M][N].
// ---------------------------------------------------------------------------
template<int KCW>   // k32-steps per wave; K = KCW*128
__global__ __launch_bounds__(TPB) void k_gemmS(
    const unsigned short* __restrict__ A0, const unsigned short* __restrict__ Wf,
    const float* __restrict__ bias, const unsigned short* __restrict__ resid,
    unsigned short* __restrict__ O0, int NTtot)
{
    constexpr int K = KCW * 128;
    __shared__ float red[12 * 4 * 64 * 4];   // 49,152 B
    int lane = threadIdx.x & 63, wave = threadIdx.x >> 6;
    int ml = lane & 15, kq = lane >> 4;
    int m0 = blockIdx.x * 64, nb = blockIdx.y;
    int N = NTtot * 16;

    const unsigned short* Ap[4];
    #pragma unroll
    for (int i = 0; i < 4; ++i) {
        int mf = (wave + i) & 3;
        Ap[i] = A0 + (size_t)(m0 + mf * 16 + ml) * K + wave * (KCW * 32) + kq * 8;
    }
    const unsigned short* Bp = Wf + ((size_t)(wave * KCW) * NTtot + nb * 4) * 512 + lane * 8;

    f32x4 acc[4][4];
    #pragma unroll
    for (int i = 0; i < 4; ++i)
        #pragma unroll
        for (int nt = 0; nt < 4; ++nt) acc[i][nt] = (f32x4){0.f, 0.f, 0.f, 0.f};

    #pragma unroll
    for (int q = 0; q < KCW; ++q) {
        short8 b[4];
        #pragma unroll
        for (int nt = 0; nt < 4; ++nt)
            b[nt] = *(const short8*)(Bp + ((size_t)q * NTtot + nt) * 512);
        short8 a[4];
        #pragma unroll
        for (int i = 0; i < 4; ++i)
            a[i] = *(const short8*)(Ap[i] + q * 32);
        #pragma unroll
        for (int i = 0; i < 4; ++i)
            #pragma unroll
            for (int nt = 0; nt < 4; ++nt)
                acc[i][nt] = __builtin_amdgcn_mfma_f32_16x16x32_bf16(a[i], b[nt], acc[i][nt], 0, 0, 0);
    }

    // write foreign slices (i=1..3) to LDS
    #pragma unroll
    for (int i = 1; i < 4; ++i) {
        int s = wave * 3 + (i - 1);
        #pragma unroll
        for (int nt = 0; nt < 4; ++nt)
            *(f32x4*)&red[(((s * 4 + nt) * 64) + lane) * 4] = acc[i][nt];
    }
    __syncthreads();
    // accumulate own slice from the 3 other waves
    #pragma unroll
    for (int w2 = 0; w2 < 4; ++w2) {
        if (w2 == wave) continue;
        int i = (wave - w2) & 3;
        int s = w2 * 3 + (i - 1);
        #pragma unroll
        for (int nt = 0; nt < 4; ++nt) {
            f32x4 v = *(const f32x4*)&red[(((s * 4 + nt) * 64) + lane) * 4];
            acc[0][nt] += v;
        }
    }

    // epilogue: rows m0 + wave*16 + kq*4 + r
    int mrow = m0 + wave * 16 + kq * 4;
    unsigned short* Ot = O0 + (size_t)mrow * N + nb * 64;
    const unsigned short* Rt = resid ? resid + (size_t)mrow * N + nb * 64 : nullptr;
    #pragma unroll
    for (int nt = 0; nt < 4; ++nt) {
        float bv = bias[nb * 64 + nt * 16 + ml];
        #pragma unroll
        for (int r = 0; r < 4; ++r) {
            float v = fmaxf(acc[0][nt][r] + bv, 0.f);
            if (Rt) v += bf2f(Rt[(size_t)r * N + nt * 16 + ml]);
            Ot[(size_t)r * N + nt * 16 + ml] = f2bf(v);
        }
    }
}

// ---------------------------------------------------------------------------
// 3x3 conv GEMM: A direct from global (channels-last, L1 tap reuse), B staged
// in LDS double-buffered by (chunk,ky) groups. Block = 64px x 4 rows, TPB=256
// (wave = one pixel row). Per wave: 16 MFMA per 4 global A-loads + 4 LDS
// B-reads; 192 MFMAs/block between barriers. LDS 48 KB -> 3 blocks/CU.
// ---------------------------------------------------------------------------
template<int CHUNKS>   // input channels = CHUNKS*64
__global__ __launch_bounds__(TPB) void k_conv3g(
    const unsigned short* __restrict__ A0, const unsigned short* __restrict__ Wf,
    const float* __restrict__ bias, unsigned short* __restrict__ O0,
    int AP, int tilesX, int OMS, int OP, int NTtot)
{
    constexpr int Cs  = CHUNKS * 64;
    constexpr int KC2 = CHUNKS * 2;          // k32-steps per tap (whole K)
    __shared__ unsigned short Bs[2][12288];  // 2 x 24,576 B

    int lane = threadIdx.x & 63, wave = threadIdx.x >> 6;   // wave 0..3
    int ml = lane & 15, kq = lane >> 4;
    int nb = blockIdx.y;
    int tileX = blockIdx.x % tilesX, tileY = blockIdx.x / tilesX;
    int gx0 = tileX * 64, gy = tileY * 4 + wave;

    const unsigned short* Abase = A0 + (size_t)(gy - 1) * AP
                                     + (size_t)(gx0 + ml - 1) * Cs + kq * 8;

    f32x4 acc[4][4];
    #pragma unroll
    for (int mf = 0; mf < 4; ++mf)
        #pragma unroll
        for (int nt = 0; nt < 4; ++nt) acc[mf][nt] = (f32x4){0.f, 0.f, 0.f, 0.f};

    const int G = CHUNKS * 3;   // groups: (chunk, ky)

    auto stageB = [&](int g) {
        int ch = g / 3, ky = g - (g / 3) * 3;
        unsigned short* bd = Bs[g & 1];
        #pragma unroll
        for (int it = 0; it < 6; ++it) {
            int u = threadIdx.x + it * TPB;     // 1536 int4 loads total
            int e = u * 8;
            int kxq = e >> 11;                  // [kx*2+q] 0..5
            int rem = e & 2047;
            int kx = kxq >> 1, q = kxq & 1;
            const unsigned short* src = Wf
                + ((size_t)((ky * 3 + kx) * KC2 + ch * 2 + q) * NTtot + nb * 4) * 512 + rem;
            *(int4*)&bd[e] = *(const int4*)src;
        }
    };

    stageB(0);
    __syncthreads();
    for (int g = 0; g < G; ++g) {
        if (g + 1 < G) stageB(g + 1);
        int ch = g / 3, ky = g - (g / 3) * 3;
        const unsigned short* Ar = Abase + (size_t)ky * AP + ch * 64;
        const unsigned short* Bb = &Bs[g & 1][lane * 8];
        #pragma unroll
        for (int kx = 0; kx < 3; ++kx) {
            #pragma unroll
            for (int q = 0; q < 2; ++q) {
                short8 b[4];
                #pragma unroll
                for (int nt = 0; nt < 4; ++nt)
                    b[nt] = *(const short8*)(Bb + (kx * 2 + q) * 2048 + nt * 512);
                short8 a[4];
                #pragma unroll
                for (int mf = 0; mf < 4; ++mf)
                    a[mf] = *(const short8*)(Ar + (size_t)(kx + mf * 16) * Cs + q * 32);
                #pragma unroll
                for (int mf = 0; mf < 4; ++mf)
                    #pragma unroll
                    for (int nt = 0; nt < 4; ++nt)
                        acc[mf][nt] = __builtin_amdgcn_mfma_f32_16x16x32_bf16(a[mf], b[nt], acc[mf][nt], 0, 0, 0);
            }
        }
        __syncthreads();
    }

    unsigned short* Orow = O0 + (size_t)gy * OP + (size_t)nb * 64;
    #pragma unroll
    for (int mf = 0; mf < 4; ++mf) {
        int gx = gx0 + mf * 16 + kq * 4;
        #pragma unroll
        for (int nt = 0; nt < 4; ++nt) {
            float bv = bias[nb * 64 + nt * 16 + ml];
            #pragma unroll
            for (int r = 0; r < 4; ++r) {
                float v = fmaxf(acc[mf][nt][r] + bv, 0.f);
                Orow[(size_t)(gx + r) * OMS + nt * 16 + ml] = f2bf(v);
            }
        }
    }
}

// ---------------------------------------------------------------------------
// Generic MFMA GEMM (global-direct), MW m-frags per wave. Used for conv1 and
// convT (ct=1: blockIdx.z = tap, parity-shifted output).
// ---------------------------------------------------------------------------
template<int MW, int KC>
__global__ __launch_bounds__(TPB) void k_gemm(
    const unsigned short* __restrict__ A0, const unsigned short* __restrict__ Wf,
    const float* __restrict__ bias, const unsigned short* __restrict__ resid, int RS,
    unsigned short* __restrict__ O0,
    int Cs, int AP, int Wimg, int OMS, int OP,
    int T, TapOffs toffs, int NTtot, int relu, int ct, int ctDy, int ctDx)
{
    int lane = threadIdx.x & 63, wave = threadIdx.x >> 6;
    int ml = lane & 15, kq = lane >> 4;
    int nb = blockIdx.y;

    const unsigned short* Wb = Wf;
    unsigned short* Ob = O0;
    if (ct) {
        int tp = blockIdx.z;
        Wb += (size_t)(tp * KC) * NTtot * 512;
        int dy = 1 - (tp >> 1), dx = 1 - (tp & 1);   // jax conv_transpose tap flip
        Ob += (size_t)dy * ctDy + (size_t)dx * ctDx;
    }
    const unsigned short* WbB = Wb + (size_t)(nb * 4) * 512 + lane * 8;

    int fy[MW], fx[MW];
    const unsigned short* Af[MW];
    #pragma unroll
    for (int f = 0; f < MW; ++f) {
        int mf = (blockIdx.x * 4 + wave) * (16 * MW) + f * 16;
        int y = mf / Wimg, x = mf - y * Wimg;
        fy[f] = y; fx[f] = x;
        Af[f] = A0 + (size_t)y * AP + (size_t)(x + ml) * Cs + kq * 8;
    }

    f32x4 acc[MW][4];
    #pragma unroll
    for (int f = 0; f < MW; ++f)
        #pragma unroll
        for (int nt = 0; nt < 4; ++nt) acc[f][nt] = (f32x4){0.f, 0.f, 0.f, 0.f};

    for (int tp = 0; tp < T; ++tp) {
        int toff = toffs.o[tp];
        const unsigned short* Wt = WbB + (size_t)(tp * KC) * NTtot * 512;
        #pragma unroll
        for (int q = 0; q < KC; ++q) {
            short8 b[4];
            #pragma unroll
            for (int nt = 0; nt < 4; ++nt)
                b[nt] = *(const short8*)(Wt + (size_t)q * NTtot * 512 + nt * 512);
            short8 a[MW];
            #pragma unroll
            for (int f = 0; f < MW; ++f)
                a[f] = *(const short8*)(Af[f] + toff + q * 32);
            #pragma unroll
            for (int f = 0; f < MW; ++f)
                #pragma unroll
                for (int nt = 0; nt < 4; ++nt)
                    acc[f][nt] = __builtin_amdgcn_mfma_f32_16x16x32_bf16(a[f], b[nt], acc[f][nt], 0, 0, 0);
        }
    }

    #pragma unroll
    for (int f = 0; f < MW; ++f) {
        unsigned short* Ot = Ob + (size_t)fy[f] * OP + (size_t)(fx[f] + kq * 4) * OMS + (size_t)nb * 64;
        int mg0 = (blockIdx.x * 4 + wave) * (16 * MW) + f * 16 + kq * 4;
        #pragma unroll
        for (int nt = 0; nt < 4; ++nt) {
            int ng = nb * 64 + nt * 16 + ml;
            float bv = bias[ng];
            #pragma unroll
            for (int r = 0; r < 4; ++r) {
                float v = acc[f][nt][r] + bv;
                if (relu) v = fmaxf(v, 0.f);
                if (resid) v += bf2f(resid[(size_t)(mg0 + r) * RS + ng]);
                Ot[(size_t)r * OMS + nt * 16 + ml] = f2bf(v);
            }
        }
    }
}

// ---------------- fused weight packing (all 15 tensors, one dispatch) -------
struct PackArgs {
    const float* w[15];
    int cum[16];
    int mode[15], KC[15], NT[15], K[15], N[15];
};
__global__ __launch_bounds__(TPB) void k_pack_all(
    PackArgs pa, unsigned short* __restrict__ dst, int total)
{
    int idx = blockIdx.x * TPB + threadIdx.x;
    if (idx >= total) return;
    int e = 0;
    #pragma unroll
    for (int i = 1; i < 15; ++i) e += (idx >= pa.cum[i]);
    int local = idx - pa.cum[e];
    const float* w = pa.w[e];
    int KC = pa.KC[e], NT = pa.NT[e], K = pa.K[e], N = pa.N[e], mode = pa.mode[e];

    int j = local & 7, l = (local >> 3) & 63;
    int r = local >> 9;
    int ntg = r % NT; int r2 = r / NT;
    int q = r2 % KC; int tp = r2 / KC;
    int k = q * 32 + (l >> 4) * 8 + j;
    int n = ntg * 16 + (l & 15);
    float v = 0.f;
    if (mode == 0) { int ky = tp / 3, kx = tp % 3; v = w[(size_t)(n * K + k) * 9 + ky * 3 + kx]; }
    else if (mode == 1) { v = w[(size_t)k * N + n]; }
    else if (mode == 2) { v = w[((size_t)tp * K + k) * N + n]; }
    else { if (k < 27) { int tap = k / 3, c = k % 3; int ky = tap / 3, kx = tap % 3;
                         v = w[((n * 3 + c) * 3 + ky) * 3 + kx]; } }
    dst[idx] = f2bf(v);
}

// ---------------- fused pad-ring zeroing (all buffers, one dispatch) --------
struct ZArgs { int off[10]; int cum[11]; int W2[10]; int H2[10]; int Cs[10]; };
__global__ __launch_bounds__(TPB) void k_zero_all(
    ZArgs za, unsigned short* __restrict__ W, int total)
{
    int idx = blockIdx.x * TPB + threadIdx.x;
    if (idx >= total) return;
    int e = 0;
    #pragma unroll
    for (int i = 1; i < 10; ++i) e += (idx >= za.cum[i]);
    int local = idx - za.cum[e];
    int W2 = za.W2[e], H2 = za.H2[e], Cs = za.Cs[e];
    int topbot = 2 * W2 * Cs;
    int iy, ix, c;
    if (local < topbot) {
        int row = local / (W2 * Cs); int rest = local - row * (W2 * Cs);
        iy = row ? (H2 - 1) : 0; ix = rest / Cs; c = rest - (rest / Cs) * Cs;
    } else {
        int idx2 = local - topbot;
        int per = (H2 - 2) * Cs;
        int side = idx2 / per; int rest = idx2 - side * per;
        iy = 1 + rest / Cs; ix = side ? (W2 - 1) : 0; c = rest - (rest / Cs) * Cs;
    }
    W[(size_t)za.off[e] + ((size_t)iy * W2 + ix) * Cs + c] = 0;
}

// ---------------- conv1 im2col: x fp32 [3][256][256] -> xcol bf16 [65536][32]
__global__ __launch_bounds__(TPB) void k_im2col(
    const float* __restrict__ x, unsigned short* __restrict__ xcol)
{
    int idx = blockIdx.x * TPB + threadIdx.x;
    if (idx >= 65536 * 32) return;
    int k = idx & 31, m = idx >> 5;
    int y = m >> 8, xx = m & 255;
    float v = 0.f;
    if (k < 27) {
        int tap = k / 3, c = k - tap * 3;
        int ty = tap / 3, tx = tap % 3;
        int yy = y + ty - 1, xp = xx + tx - 1;
        if (yy >= 0 && yy < 256 && xp >= 0 && xp < 256)
            v = x[c * 65536 + yy * 256 + xp];
    }
    xcol[idx] = f2bf(v);
}

// ---------------- maxpool 2x2 channels-last (strided in/out) ----------------
__global__ __launch_bounds__(TPB) void k_maxpool(
    const unsigned short* __restrict__ inI, unsigned short* __restrict__ outI,
    int Wo, int C4, int CsIn, int inPitch, int CsOut, int outPitch, int total)
{
    int idx = blockIdx.x * TPB + threadIdx.x;
    if (idx >= total) return;
    int c4 = idx % C4; int p = idx / C4;
    int x = p % Wo, y = p / Wo;
    const unsigned short* ip = inI + (size_t)(2 * y) * inPitch + (size_t)(2 * x) * CsIn + c4 * 4;
    ushort4 a = *(const ushort4*)(ip);
    ushort4 b = *(const ushort4*)(ip + CsIn);
    ushort4 c = *(const ushort4*)(ip + inPitch);
    ushort4 d = *(const ushort4*)(ip + inPitch + CsIn);
    ushort4 o;
    o.x = f2bf(fmaxf(fmaxf(bf2f(a.x), bf2f(b.x)), fmaxf(bf2f(c.x), bf2f(d.x))));
    o.y = f2bf(fmaxf(fmaxf(bf2f(a.y), bf2f(b.y)), fmaxf(bf2f(c.y), bf2f(d.y))));
    o.z = f2bf(fmaxf(fmaxf(bf2f(a.z), bf2f(b.z)), fmaxf(bf2f(c.z), bf2f(d.z))));
    o.w = f2bf(fmaxf(fmaxf(bf2f(a.w), bf2f(b.w)), fmaxf(bf2f(c.w), bf2f(d.w))));
    *(ushort4*)(outI + (size_t)y * outPitch + (size_t)x * CsOut + c4 * 4) = o;
}

// ---------------- graph aggregation on 66x66 grid, node-major bf16 ----------
__global__ __launch_bounds__(TPB) void k_gagg(
    const unsigned short* __restrict__ X, unsigned short* __restrict__ agg,
    int C, int total)
{
    int idx = blockIdx.x * TPB + threadIdx.x;
    if (idx >= total) return;
    int C4 = C >> 2;
    int c4 = idx % C4; int n = idx / C4;
    int i = n / 66, j = n - i * 66;
    size_t base = (size_t)n * C + c4 * 4;
    ushort4 s = *(const ushort4*)(X + base);
    float v0 = bf2f(s.x), v1 = bf2f(s.y), v2 = bf2f(s.z), v3 = bf2f(s.w);
    float cnt = 1.f;
    if (i > 0)  { ushort4 u = *(const ushort4*)(X + base - (size_t)66 * C);
                  v0 += bf2f(u.x); v1 += bf2f(u.y); v2 += bf2f(u.z); v3 += bf2f(u.w); cnt += 1.f; }
    if (i < 65) { ushort4 u = *(const ushort4*)(X + base + (size_t)66 * C);
                  v0 += bf2f(u.x); v1 += bf2f(u.y); v2 += bf2f(u.z); v3 += bf2f(u.w); cnt += 1.f; }
    if (j > 0)  { ushort4 u = *(const ushort4*)(X + base - C);
                  v0 += bf2f(u.x); v1 += bf2f(u.y); v2 += bf2f(u.z); v3 += bf2f(u.w); cnt += 1.f; }
    if (j < 65) { ushort4 u = *(const ushort4*)(X + base + C);
                  v0 += bf2f(u.x); v1 += bf2f(u.y); v2 += bf2f(u.z); v3 += bf2f(u.w); cnt += 1.f; }
    float inv = 1.f / cnt;
    ushort4 o;
    o.x = f2bf(v0 * inv); o.y = f2bf(v1 * inv); o.z = f2bf(v2 * inv); o.w = f2bf(v3 * inv);
    *(ushort4*)(agg + base) = o;
}

// ---------------- final conv 64->1, fp32 out --------------------------------
__global__ __launch_bounds__(TPB) void k_outconv(
    const unsigned short* __restrict__ vI, const float* __restrict__ ow,
    const float* __restrict__ ob, float* __restrict__ out)
{
    __shared__ float wl[576];
    for (int i = threadIdx.x; i < 576; i += TPB) wl[i] = ow[i];
    __syncthreads();
    int p = blockIdx.x * TPB + threadIdx.x;
    int y = p >> 8, x = p & 255;
    float acc = ob[0];
    #pragma unroll
    for (int ky = 0; ky < 3; ++ky)
        #pragma unroll
        for (int kx = 0; kx < 3; ++kx) {
            const unsigned short* ip = vI + (size_t)((y + ky - 1) * 258 + (x + kx - 1)) * 64;
            int wb = ky * 3 + kx;
            for (int c = 0; c < 64; c += 4) {
                ushort4 uv = *(const ushort4*)(ip + c);
                acc += bf2f(uv.x) * wl[c * 9 + wb] + bf2f(uv.y) * wl[(c + 1) * 9 + wb]
                     + bf2f(uv.z) * wl[(c + 2) * 9 + wb] + bf2f(uv.w) * wl[(c + 3) * 9 + wb];
            }
        }
    out[p] = acc;
}

static inline TapOffs zero_toffs() { TapOffs t = {}; return t; }

extern "C" void kernel_launch(void* const* d_in, const int* in_sizes, int n_in,
                              void* d_out, int out_size, void* d_ws, size_t ws_size,
                              hipStream_t stream) {
    const float* x    = (const float*)d_in[0];
    const float* d1w1 = (const float*)d_in[1];  const float* d1b1 = (const float*)d_in[2];
    const float* d1w2 = (const float*)d_in[3];  const float* d1b2 = (const float*)d_in[4];
    const float* d2w1 = (const float*)d_in[5];  const float* d2b1 = (const float*)d_in[6];
    const float* d2w2 = (const float*)d_in[7];  const float* d2b2 = (const float*)d_in[8];
    const float* md1w = (const float*)d_in[9];  const float* md1b = (const float*)d_in[10];
    const float* md2w = (const float*)d_in[11]; const float* md2b = (const float*)d_in[12];
    const float* mbw  = (const float*)d_in[13]; const float* mbb  = (const float*)d_in[14];
    const float* mu1w = (const float*)d_in[15]; const float* mu1b = (const float*)d_in[16];
    const float* mu2w = (const float*)d_in[17]; const float* mu2b = (const float*)d_in[18];
    const float* u3tw = (const float*)d_in[19]; const float* u3tb = (const float*)d_in[20];
    const float* u3w1 = (const float*)d_in[21]; const float* u3b1 = (const float*)d_in[22];
    const float* u3w2 = (const float*)d_in[23]; const float* u3b2 = (const float*)d_in[24];
    const float* u4tw = (const float*)d_in[25]; const float* u4tb = (const float*)d_in[26];
    const float* u4w1 = (const float*)d_in[27]; const float* u4b1 = (const float*)d_in[28];
    const float* u4w2 = (const float*)d_in[29]; const float* u4b2 = (const float*)d_in[30];
    const float* ow   = (const float*)d_in[31]; const float* ob   = (const float*)d_in[32];
    float* out = (float*)d_out;

    unsigned short* W = (unsigned short*)d_ws;

    // ---- flat arena (elem offsets, bf16) ----
    const size_t XCOL = 0;          // 2,097,152
    const size_t A1   = 2097152;    // 258*258*64
    const size_t CAT4 = 6357248;    // 258*258*128
    const size_t P1   = 14877440;   // 130*130*64
    const size_t T2   = 15959040;   // 130*130*128
    const size_t CAT3 = 18122240;   // 130*130*256
    const size_t X0   = 22448640;   // 66*66*128
    const size_t BP1  = 23006208;   // 4608*256
    const size_t BP2  = 24185856;   // 4608*512
    const size_t XB   = 26545152;   // 4608*1024
    const size_t XC   = 31263744;   // 4608*512
    const size_t XD   = 33623040;   // 4608*256
    const size_t V3A  = 34802688;   // 130*130*128
    const size_t V3B  = 36965888;   // 130*130*128
    const size_t V4A  = 39129088;   // 258*258*64
    const size_t V4B  = 43389184;   // 258*258*64
    const size_t AGG  = 47649280;   // 4608*1024
    const size_t WP   = 52367872;   // packed weights 2,320,384

    const size_t a1I   = A1 + 259 * 64;
    const size_t cat4I = CAT4 + 259 * 128;
    const size_t p1I   = P1 + 131 * 64;
    const size_t t2I   = T2 + 131 * 128;
    const size_t cat3I = CAT3 + 131 * 256;
    const size_t X0I   = X0 + 67 * 128;
    const size_t XdI   = XD + 67 * 256;
    const size_t v3aI  = V3A + 131 * 128;
    const size_t v3bI  = V3B + 131 * 128;
    const size_t v4aI  = V4A + 259 * 64;
    const size_t v4bI  = V4B + 259 * 64;

    dim3 blk(TPB);
    const int BIG = 1 << 28;

    // ---- fused pad-ring zeroing ----
    {
        ZArgs za;
        const int off[10] = {(int)A1,(int)CAT4,(int)P1,(int)T2,(int)CAT3,(int)V3A,(int)V3B,(int)V4A,(int)V4B,(int)X0};
        const int w2 [10] = {258,258,130,130,130,130,130,258,258,66};
        const int h2 [10] = {258,258,130,130,130,130,130,258,258,66};
        const int cs [10] = {64,128,64,128,256,128,128,64,64,128};
        int cum = 0;
        for (int i = 0; i < 10; ++i) {
            za.off[i]=off[i]; za.W2[i]=w2[i]; za.H2[i]=h2[i]; za.Cs[i]=cs[i];
            za.cum[i]=cum; cum += (w2[i]*h2[i] - (w2[i]-2)*(h2[i]-2))*cs[i];
        }
        za.cum[10]=cum;
        k_zero_all<<<dim3((cum + TPB - 1) / TPB), blk, 0, stream>>>(za, W, cum);
    }

    // ---- fused weight packing ----
    {
        PackArgs pa;
        const float* ws_[15] = {d1w1,d1w2,d2w1,d2w2,md1w,md2w,mbw,mu1w,mu2w,u3tw,u3w1,u3w2,u4tw,u4w1,u4w2};
        const int mode[15] = {3,0,0,0,1,1,1,1,1,2,0,0,2,0,0};
        const int kc [15] = {1,2,2,4,4,8,16,32,16,8,8,4,4,4,2};
        const int nt [15] = {4,4,8,8,16,32,64,32,16,8,8,8,4,4,4};
        const int kk [15] = {32,64,64,128,128,256,512,1024,512,256,256,128,128,128,64};
        const int nn [15] = {64,64,128,128,256,512,1024,512,256,128,128,128,64,64,64};
        const int tt [15] = {1,9,9,9,1,1,1,1,1,4,9,9,4,9,9};
        int cum = 0;
        for (int i = 0; i < 15; ++i) {
            pa.w[i]=ws_[i]; pa.mode[i]=mode[i]; pa.KC[i]=kc[i]; pa.NT[i]=nt[i];
            pa.K[i]=kk[i]; pa.N[i]=nn[i]; pa.cum[i]=cum;
            cum += tt[i]*kc[i]*nt[i]*512;
        }
        pa.cum[15]=cum;
        k_pack_all<<<dim3((cum + TPB - 1) / TPB), blk, 0, stream>>>(pa, W + WP, cum);
    }
    const size_t pw_d1w1=WP+0, pw_d1w2=WP+2048, pw_d2w1=WP+38912, pw_d2w2=WP+112640,
        pw_md1=WP+260096, pw_md2=WP+292864, pw_mb=WP+423936, pw_mu1=WP+948224,
        pw_mu2=WP+1472512, pw_u3t=WP+1603584, pw_u3w1=WP+1734656, pw_u3w2=WP+2029568,
        pw_u4t=WP+2177024, pw_u4w1=WP+2209792, pw_u4w2=WP+2283520;

    // ---- encoder ----
    k_im2col<<<dim3(8192), blk, 0, stream>>>(x, W + XCOL);
    k_gemm<2,1><<<dim3(512,1), blk, 0, stream>>>(W + XCOL, W + pw_d1w1, d1b1, nullptr, 0,
        W + a1I, 32, 8192, 256, 64, 258*64, 1, zero_toffs(), 4, 1, 0,0,0);
    k_conv3g<1><<<dim3(256,1), blk, 0, stream>>>(W + a1I, W + pw_d1w2, d1b2,
        W + cat4I, 258*64, 4, 128, 258*128, 4);
    k_maxpool<<<dim3(1024), blk, 0, stream>>>(W + cat4I, W + p1I, 128, 16, 128, 258*128, 64, 130*64, 128*128*16);
    k_conv3g<1><<<dim3(64,2), blk, 0, stream>>>(W + p1I, W + pw_d2w1, d2b1,
        W + t2I, 130*64, 2, 128, 130*128, 8);
    k_conv3g<2><<<dim3(64,2), blk, 0, stream>>>(W + t2I, W + pw_d2w2, d2b2,
        W + cat3I, 130*128, 2, 256, 130*256, 8);
    k_maxpool<<<dim3(512), blk, 0, stream>>>(W + cat3I, W + X0I, 64, 32, 256, 130*256, 128, 66*128, 64*64*32);

    // ---- GNN on 66x66 padded grid (K-split GEMMs) ----
    k_gagg<<<dim3(545), blk, 0, stream>>>(W + X0, W + AGG, 128, 4356*32);
    k_gemmS<1><<<dim3(72,4), blk, 0, stream>>>(W + AGG, W + pw_md1, md1b, nullptr, W + BP1, 16);
    k_gagg<<<dim3(1089), blk, 0, stream>>>(W + BP1, W + AGG, 256, 4356*64);
    k_gemmS<2><<<dim3(72,8), blk, 0, stream>>>(W + AGG, W + pw_md2, md2b, nullptr, W + BP2, 32);
    k_gagg<<<dim3(2178), blk, 0, stream>>>(W + BP2, W + AGG, 512, 4356*128);
    k_gemmS<4><<<dim3(72,16), blk, 0, stream>>>(W + AGG, W + pw_mb, mbb, nullptr, W + XB, 64);
    k_gagg<<<dim3(4356), blk, 0, stream>>>(W + XB, W + AGG, 1024, 4356*256);
    k_gemmS<8><<<dim3(72,8), blk, 0, stream>>>(W + AGG, W + pw_mu1, mu1b, W + BP2, W + XC, 32);
    k_gagg<<<dim3(2178), blk, 0, stream>>>(W + XC, W + AGG, 512, 4356*128);
    k_gemmS<4><<<dim3(72,4), blk, 0, stream>>>(W + AGG, W + pw_mu2, mu2b, W + BP1, W + XD, 16);

    // ---- decoder stage 3 ----
    k_gemm<2,8><<<dim3(32,2,4), blk, 0, stream>>>(W + XdI, W + pw_u3t, u3tb, nullptr, 0,
        W + cat3I + 128, 256, 66*256, 64, 512, 2*130*256, 1, zero_toffs(), 8, 0, 1, 130*256, 256);
    k_conv3g<4><<<dim3(64,2), blk, 0, stream>>>(W + cat3I, W + pw_u3w1, u3b1,
        W + v3aI, 130*256, 2, 128, 130*128, 8);
    k_conv3g<2><<<dim3(64,2), blk, 0, stream>>>(W + v3aI, W + pw_u3w2, u3b2,
        W + v3bI, 130*128, 2, 128, 130*128, 8);

    // ---- decoder stage 4 ----
    k_gemm<2,4><<<dim3(128,1,4), blk, 0, stream>>>(W + v3bI, W + pw_u4t, u4tb, nullptr, 0,
        W + cat4I + 64, 128, 130*128, 128, 256, 2*258*128, 1, zero_toffs(), 4, 0, 1, 258*128, 128);
    k_conv3g<2><<<dim3(256,1), blk, 0, stream>>>(W + cat4I, W + pw_u4w1, u4b1,
        W + v4aI, 258*128, 4, 64, 258*64, 4);
    k_conv3g<1><<<dim3(256,1), blk, 0, stream>>>(W + v4aI, W + pw_u4w2, u4b2,
        W + v4bI, 258*64, 4, 64, 258*64, 4);

    // ---- output conv 64->1, fp32 ----
    k_outconv<<<dim3(256), blk, 0, stream>>>(W + v4bI, ow, ob, out);
}

// Round 7
// 395.251 us; speedup vs baseline: 1.3003x; 1.1275x over previous
//
#include <hip/hip_runtime.h>
#include <cstddef>

#define TPB 256

typedef __attribute__((ext_vector_type(8))) short short8;
typedef __attribute__((ext_vector_type(4))) float f32x4;

__device__ inline unsigned short f2bf(float f) {
    unsigned int u = __builtin_bit_cast(unsigned int, f);
    u += 0x7fffu + ((u >> 16) & 1u);
    return (unsigned short)(u >> 16);
}
__device__ inline float bf2f(unsigned short h) {
    unsigned int u = ((unsigned int)h) << 16;
    return __builtin_bit_cast(float, u);
}

struct TapOffs { int o[9]; };

// ---------------------------------------------------------------------------
// 3x3 conv GEMM, m-split: block = MW*64 px (one row strip) x 64 n. 4 waves,
// wave w owns px [gx0 + w*MW*16, +MW*16) -> MW m-frags, no cross-wave reduce.
// A direct from global (channels-last, pad ring valid), B staged in LDS
// (fragment order, lane*16B conflict-free), double-buffered by (chunk,ky)
// groups. MW=2 for 256^2 imgs (512 blocks), MW=1 for 128^2 (512 blocks incl
// grid.y) -> 2 blocks/CU, 8 waves/CU (vs R6's 1 block/CU, 4 waves/CU).
// mfma_f32_16x16x32_bf16: A[m=lane&15][k=(lane>>4)*8+j], B[k][n=lane&15],
// D: col(n)=lane&15, row(m)=(lane>>4)*4+reg.
// ---------------------------------------------------------------------------
template<int CHUNKS, int MW>   // input channels = CHUNKS*64
__global__ __launch_bounds__(TPB) void k_conv3s(
    const unsigned short* __restrict__ A0, const unsigned short* __restrict__ Wf,
    const float* __restrict__ bias, unsigned short* __restrict__ O0,
    int AP, int tilesX, int OMS, int OP, int NTtot)
{
    constexpr int Cs  = CHUNKS * 64;
    constexpr int KC2 = CHUNKS * 2;          // k32-steps per tap (whole K)
    __shared__ unsigned short Bs[2][12288];  // 2 x 24,576 B

    int lane = threadIdx.x & 63, wave = threadIdx.x >> 6;
    int ml = lane & 15, kq = lane >> 4;
    int nb = blockIdx.y;
    int tileX = blockIdx.x % tilesX, gy = blockIdx.x / tilesX;
    int gx0 = tileX * (MW * 64) + wave * (MW * 16);

    const unsigned short* Abase = A0 + (size_t)(gy - 1) * AP
                                     + (size_t)(gx0 + ml - 1) * Cs + kq * 8;

    f32x4 acc[MW][4];
    #pragma unroll
    for (int mf = 0; mf < MW; ++mf)
        #pragma unroll
        for (int nt = 0; nt < 4; ++nt) acc[mf][nt] = (f32x4){0.f, 0.f, 0.f, 0.f};

    const int G = CHUNKS * 3;   // groups: (chunk, ky)

    auto stageB = [&](int g) {
        int ch = g / 3, ky = g - (g / 3) * 3;
        unsigned short* bd = Bs[g & 1];
        #pragma unroll
        for (int it = 0; it < 6; ++it) {
            int u = threadIdx.x + it * TPB;     // 1536 int4 loads total
            int e = u * 8;
            int kxq = e >> 11;                  // [kx*2+q] 0..5
            int rem = e & 2047;
            int kx = kxq >> 1, q = kxq & 1;
            const unsigned short* src = Wf
                + ((size_t)((ky * 3 + kx) * KC2 + ch * 2 + q) * NTtot + nb * 4) * 512 + rem;
            *(int4*)&bd[e] = *(const int4*)src;
        }
    };

    stageB(0);
    __syncthreads();
    for (int g = 0; g < G; ++g) {
        if (g + 1 < G) stageB(g + 1);
        int ch = g / 3, ky = g - (g / 3) * 3;
        const unsigned short* Ar = Abase + (size_t)ky * AP + ch * 64;
        const unsigned short* Bb = &Bs[g & 1][lane * 8];
        #pragma unroll
        for (int kx = 0; kx < 3; ++kx) {
            #pragma unroll
            for (int q = 0; q < 2; ++q) {
                short8 b[4];
                #pragma unroll
                for (int nt = 0; nt < 4; ++nt)
                    b[nt] = *(const short8*)(Bb + (kx * 2 + q) * 2048 + nt * 512);
                short8 a[MW];
                #pragma unroll
                for (int mf = 0; mf < MW; ++mf)
                    a[mf] = *(const short8*)(Ar + (size_t)(kx + mf * 16) * Cs + q * 32);
                #pragma unroll
                for (int mf = 0; mf < MW; ++mf)
                    #pragma unroll
                    for (int nt = 0; nt < 4; ++nt)
                        acc[mf][nt] = __builtin_amdgcn_mfma_f32_16x16x32_bf16(a[mf], b[nt], acc[mf][nt], 0, 0, 0);
            }
        }
        __syncthreads();
    }

    unsigned short* Orow = O0 + (size_t)gy * OP + (size_t)nb * 64;
    #pragma unroll
    for (int mf = 0; mf < MW; ++mf) {
        int gx = gx0 + mf * 16 + kq * 4;
        #pragma unroll
        for (int nt = 0; nt < 4; ++nt) {
            float bv = bias[nb * 64 + nt * 16 + ml];
            #pragma unroll
            for (int r = 0; r < 4; ++r) {
                float v = fmaxf(acc[mf][nt][r] + bv, 0.f);
                Orow[(size_t)(gx + r) * OMS + nt * 16 + ml] = f2bf(v);
            }
        }
    }
}

// ---------------------------------------------------------------------------
// K-split GNN GEMM: block = 64m x 64n tile, 4 waves each compute K/4, then
// LDS cross-wave reduce (rotated slice order so own slice is acc[0]).
// ---------------------------------------------------------------------------
template<int KCW>   // k32-steps per wave; K = KCW*128
__global__ __launch_bounds__(TPB) void k_gemmS(
    const unsigned short* __restrict__ A0, const unsigned short* __restrict__ Wf,
    const float* __restrict__ bias, const unsigned short* __restrict__ resid,
    unsigned short* __restrict__ O0, int NTtot)
{
    constexpr int K = KCW * 128;
    __shared__ float red[12 * 4 * 64 * 4];   // 49,152 B
    int lane = threadIdx.x & 63, wave = threadIdx.x >> 6;
    int ml = lane & 15, kq = lane >> 4;
    int m0 = blockIdx.x * 64, nb = blockIdx.y;
    int N = NTtot * 16;

    const unsigned short* Ap[4];
    #pragma unroll
    for (int i = 0; i < 4; ++i) {
        int mf = (wave + i) & 3;
        Ap[i] = A0 + (size_t)(m0 + mf * 16 + ml) * K + wave * (KCW * 32) + kq * 8;
    }
    const unsigned short* Bp = Wf + ((size_t)(wave * KCW) * NTtot + nb * 4) * 512 + lane * 8;

    f32x4 acc[4][4];
    #pragma unroll
    for (int i = 0; i < 4; ++i)
        #pragma unroll
        for (int nt = 0; nt < 4; ++nt) acc[i][nt] = (f32x4){0.f, 0.f, 0.f, 0.f};

    #pragma unroll
    for (int q = 0; q < KCW; ++q) {
        short8 b[4];
        #pragma unroll
        for (int nt = 0; nt < 4; ++nt)
            b[nt] = *(const short8*)(Bp + ((size_t)q * NTtot + nt) * 512);
        short8 a[4];
        #pragma unroll
        for (int i = 0; i < 4; ++i)
            a[i] = *(const short8*)(Ap[i] + q * 32);
        #pragma unroll
        for (int i = 0; i < 4; ++i)
            #pragma unroll
            for (int nt = 0; nt < 4; ++nt)
                acc[i][nt] = __builtin_amdgcn_mfma_f32_16x16x32_bf16(a[i], b[nt], acc[i][nt], 0, 0, 0);
    }

    #pragma unroll
    for (int i = 1; i < 4; ++i) {
        int s = wave * 3 + (i - 1);
        #pragma unroll
        for (int nt = 0; nt < 4; ++nt)
            *(f32x4*)&red[(((s * 4 + nt) * 64) + lane) * 4] = acc[i][nt];
    }
    __syncthreads();
    #pragma unroll
    for (int w2 = 0; w2 < 4; ++w2) {
        if (w2 == wave) continue;
        int i = (wave - w2) & 3;
        int s = w2 * 3 + (i - 1);
        #pragma unroll
        for (int nt = 0; nt < 4; ++nt) {
            f32x4 v = *(const f32x4*)&red[(((s * 4 + nt) * 64) + lane) * 4];
            acc[0][nt] += v;
        }
    }

    int mrow = m0 + wave * 16 + kq * 4;
    unsigned short* Ot = O0 + (size_t)mrow * N + nb * 64;
    const unsigned short* Rt = resid ? resid + (size_t)mrow * N + nb * 64 : nullptr;
    #pragma unroll
    for (int nt = 0; nt < 4; ++nt) {
        float bv = bias[nb * 64 + nt * 16 + ml];
        #pragma unroll
        for (int r = 0; r < 4; ++r) {
            float v = fmaxf(acc[0][nt][r] + bv, 0.f);
            if (Rt) v += bf2f(Rt[(size_t)r * N + nt * 16 + ml]);
            Ot[(size_t)r * N + nt * 16 + ml] = f2bf(v);
        }
    }
}

// ---------------------------------------------------------------------------
// Generic MFMA GEMM (global-direct), MW m-frags per wave. Used for conv1 and
// convT (ct=1: blockIdx.z = tap, parity-shifted output).
// ---------------------------------------------------------------------------
template<int MW, int KC>
__global__ __launch_bounds__(TPB) void k_gemm(
    const unsigned short* __restrict__ A0, const unsigned short* __restrict__ Wf,
    const float* __restrict__ bias, const unsigned short* __restrict__ resid, int RS,
    unsigned short* __restrict__ O0,
    int Cs, int AP, int Wimg, int OMS, int OP,
    int T, TapOffs toffs, int NTtot, int relu, int ct, int ctDy, int ctDx)
{
    int lane = threadIdx.x & 63, wave = threadIdx.x >> 6;
    int ml = lane & 15, kq = lane >> 4;
    int nb = blockIdx.y;

    const unsigned short* Wb = Wf;
    unsigned short* Ob = O0;
    if (ct) {
        int tp = blockIdx.z;
        Wb += (size_t)(tp * KC) * NTtot * 512;
        int dy = 1 - (tp >> 1), dx = 1 - (tp & 1);   // jax conv_transpose tap flip
        Ob += (size_t)dy * ctDy + (size_t)dx * ctDx;
    }
    const unsigned short* WbB = Wb + (size_t)(nb * 4) * 512 + lane * 8;

    int fy[MW], fx[MW];
    const unsigned short* Af[MW];
    #pragma unroll
    for (int f = 0; f < MW; ++f) {
        int mf = (blockIdx.x * 4 + wave) * (16 * MW) + f * 16;
        int y = mf / Wimg, x = mf - y * Wimg;
        fy[f] = y; fx[f] = x;
        Af[f] = A0 + (size_t)y * AP + (size_t)(x + ml) * Cs + kq * 8;
    }

    f32x4 acc[MW][4];
    #pragma unroll
    for (int f = 0; f < MW; ++f)
        #pragma unroll
        for (int nt = 0; nt < 4; ++nt) acc[f][nt] = (f32x4){0.f, 0.f, 0.f, 0.f};

    for (int tp = 0; tp < T; ++tp) {
        int toff = toffs.o[tp];
        const unsigned short* Wt = WbB + (size_t)(tp * KC) * NTtot * 512;
        #pragma unroll
        for (int q = 0; q < KC; ++q) {
            short8 b[4];
            #pragma unroll
            for (int nt = 0; nt < 4; ++nt)
                b[nt] = *(const short8*)(Wt + (size_t)q * NTtot * 512 + nt * 512);
            short8 a[MW];
            #pragma unroll
            for (int f = 0; f < MW; ++f)
                a[f] = *(const short8*)(Af[f] + toff + q * 32);
            #pragma unroll
            for (int f = 0; f < MW; ++f)
                #pragma unroll
                for (int nt = 0; nt < 4; ++nt)
                    acc[f][nt] = __builtin_amdgcn_mfma_f32_16x16x32_bf16(a[f], b[nt], acc[f][nt], 0, 0, 0);
        }
    }

    #pragma unroll
    for (int f = 0; f < MW; ++f) {
        unsigned short* Ot = Ob + (size_t)fy[f] * OP + (size_t)(fx[f] + kq * 4) * OMS + (size_t)nb * 64;
        int mg0 = (blockIdx.x * 4 + wave) * (16 * MW) + f * 16 + kq * 4;
        #pragma unroll
        for (int nt = 0; nt < 4; ++nt) {
            int ng = nb * 64 + nt * 16 + ml;
            float bv = bias[ng];
            #pragma unroll
            for (int r = 0; r < 4; ++r) {
                float v = acc[f][nt][r] + bv;
                if (relu) v = fmaxf(v, 0.f);
                if (resid) v += bf2f(resid[(size_t)(mg0 + r) * RS + ng]);
                Ot[(size_t)r * OMS + nt * 16 + ml] = f2bf(v);
            }
        }
    }
}

// ---------------- fused weight packing (all 15 tensors, one dispatch) -------
struct PackArgs {
    const float* w[15];
    int cum[16];
    int mode[15], KC[15], NT[15], K[15], N[15];
};
__global__ __launch_bounds__(TPB) void k_pack_all(
    PackArgs pa, unsigned short* __restrict__ dst, int total)
{
    int idx = blockIdx.x * TPB + threadIdx.x;
    if (idx >= total) return;
    int e = 0;
    #pragma unroll
    for (int i = 1; i < 15; ++i) e += (idx >= pa.cum[i]);
    int local = idx - pa.cum[e];
    const float* w = pa.w[e];
    int KC = pa.KC[e], NT = pa.NT[e], K = pa.K[e], N = pa.N[e], mode = pa.mode[e];

    int j = local & 7, l = (local >> 3) & 63;
    int r = local >> 9;
    int ntg = r % NT; int r2 = r / NT;
    int q = r2 % KC; int tp = r2 / KC;
    int k = q * 32 + (l >> 4) * 8 + j;
    int n = ntg * 16 + (l & 15);
    float v = 0.f;
    if (mode == 0) { int ky = tp / 3, kx = tp % 3; v = w[(size_t)(n * K + k) * 9 + ky * 3 + kx]; }
    else if (mode == 1) { v = w[(size_t)k * N + n]; }
    else if (mode == 2) { v = w[((size_t)tp * K + k) * N + n]; }
    else { if (k < 27) { int tap = k / 3, c = k % 3; int ky = tap / 3, kx = tap % 3;
                         v = w[((n * 3 + c) * 3 + ky) * 3 + kx]; } }
    dst[idx] = f2bf(v);
}

// ---------------- fused pad-ring zeroing (all buffers, one dispatch) --------
struct ZArgs { int off[10]; int cum[11]; int W2[10]; int H2[10]; int Cs[10]; };
__global__ __launch_bounds__(TPB) void k_zero_all(
    ZArgs za, unsigned short* __restrict__ W, int total)
{
    int idx = blockIdx.x * TPB + threadIdx.x;
    if (idx >= total) return;
    int e = 0;
    #pragma unroll
    for (int i = 1; i < 10; ++i) e += (idx >= za.cum[i]);
    int local = idx - za.cum[e];
    int W2 = za.W2[e], H2 = za.H2[e], Cs = za.Cs[e];
    int topbot = 2 * W2 * Cs;
    int iy, ix, c;
    if (local < topbot) {
        int row = local / (W2 * Cs); int rest = local - row * (W2 * Cs);
        iy = row ? (H2 - 1) : 0; ix = rest / Cs; c = rest - (rest / Cs) * Cs;
    } else {
        int idx2 = local - topbot;
        int per = (H2 - 2) * Cs;
        int side = idx2 / per; int rest = idx2 - side * per;
        iy = 1 + rest / Cs; ix = side ? (W2 - 1) : 0; c = rest - (rest / Cs) * Cs;
    }
    W[(size_t)za.off[e] + ((size_t)iy * W2 + ix) * Cs + c] = 0;
}

// ---------------- conv1 im2col: x fp32 [3][256][256] -> xcol bf16 [65536][32]
__global__ __launch_bounds__(TPB) void k_im2col(
    const float* __restrict__ x, unsigned short* __restrict__ xcol)
{
    int idx = blockIdx.x * TPB + threadIdx.x;
    if (idx >= 65536 * 32) return;
    int k = idx & 31, m = idx >> 5;
    int y = m >> 8, xx = m & 255;
    float v = 0.f;
    if (k < 27) {
        int tap = k / 3, c = k - tap * 3;
        int ty = tap / 3, tx = tap % 3;
        int yy = y + ty - 1, xp = xx + tx - 1;
        if (yy >= 0 && yy < 256 && xp >= 0 && xp < 256)
            v = x[c * 65536 + yy * 256 + xp];
    }
    xcol[idx] = f2bf(v);
}

// ---------------- maxpool 2x2 channels-last (strided in/out) ----------------
__global__ __launch_bounds__(TPB) void k_maxpool(
    const unsigned short* __restrict__ inI, unsigned short* __restrict__ outI,
    int Wo, int C4, int CsIn, int inPitch, int CsOut, int outPitch, int total)
{
    int idx = blockIdx.x * TPB + threadIdx.x;
    if (idx >= total) return;
    int c4 = idx % C4; int p = idx / C4;
    int x = p % Wo, y = p / Wo;
    const unsigned short* ip = inI + (size_t)(2 * y) * inPitch + (size_t)(2 * x) * CsIn + c4 * 4;
    ushort4 a = *(const ushort4*)(ip);
    ushort4 b = *(const ushort4*)(ip + CsIn);
    ushort4 c = *(const ushort4*)(ip + inPitch);
    ushort4 d = *(const ushort4*)(ip + inPitch + CsIn);
    ushort4 o;
    o.x = f2bf(fmaxf(fmaxf(bf2f(a.x), bf2f(b.x)), fmaxf(bf2f(c.x), bf2f(d.x))));
    o.y = f2bf(fmaxf(fmaxf(bf2f(a.y), bf2f(b.y)), fmaxf(bf2f(c.y), bf2f(d.y))));
    o.z = f2bf(fmaxf(fmaxf(bf2f(a.z), bf2f(b.z)), fmaxf(bf2f(c.z), bf2f(d.z))));
    o.w = f2bf(fmaxf(fmaxf(bf2f(a.w), bf2f(b.w)), fmaxf(bf2f(c.w), bf2f(d.w))));
    *(ushort4*)(outI + (size_t)y * outPitch + (size_t)x * CsOut + c4 * 4) = o;
}

// ---------------- graph aggregation on 66x66 grid, node-major bf16 ----------
__global__ __launch_bounds__(TPB) void k_gagg(
    const unsigned short* __restrict__ X, unsigned short* __restrict__ agg,
    int C, int total)
{
    int idx = blockIdx.x * TPB + threadIdx.x;
    if (idx >= total) return;
    int C4 = C >> 2;
    int c4 = idx % C4; int n = idx / C4;
    int i = n / 66, j = n - i * 66;
    size_t base = (size_t)n * C + c4 * 4;
    ushort4 s = *(const ushort4*)(X + base);
    float v0 = bf2f(s.x), v1 = bf2f(s.y), v2 = bf2f(s.z), v3 = bf2f(s.w);
    float cnt = 1.f;
    if (i > 0)  { ushort4 u = *(const ushort4*)(X + base - (size_t)66 * C);
                  v0 += bf2f(u.x); v1 += bf2f(u.y); v2 += bf2f(u.z); v3 += bf2f(u.w); cnt += 1.f; }
    if (i < 65) { ushort4 u = *(const ushort4*)(X + base + (size_t)66 * C);
                  v0 += bf2f(u.x); v1 += bf2f(u.y); v2 += bf2f(u.z); v3 += bf2f(u.w); cnt += 1.f; }
    if (j > 0)  { ushort4 u = *(const ushort4*)(X + base - C);
                  v0 += bf2f(u.x); v1 += bf2f(u.y); v2 += bf2f(u.z); v3 += bf2f(u.w); cnt += 1.f; }
    if (j < 65) { ushort4 u = *(const ushort4*)(X + base + C);
                  v0 += bf2f(u.x); v1 += bf2f(u.y); v2 += bf2f(u.z); v3 += bf2f(u.w); cnt += 1.f; }
    float inv = 1.f / cnt;
    ushort4 o;
    o.x = f2bf(v0 * inv); o.y = f2bf(v1 * inv); o.z = f2bf(v2 * inv); o.w = f2bf(v3 * inv);
    *(ushort4*)(agg + base) = o;
}

// ---------------- final conv 64->1, fp32 out --------------------------------
__global__ __launch_bounds__(TPB) void k_outconv(
    const unsigned short* __restrict__ vI, const float* __restrict__ ow,
    const float* __restrict__ ob, float* __restrict__ out)
{
    __shared__ float wl[576];
    for (int i = threadIdx.x; i < 576; i += TPB) wl[i] = ow[i];
    __syncthreads();
    int p = blockIdx.x * TPB + threadIdx.x;
    int y = p >> 8, x = p & 255;
    float acc = ob[0];
    #pragma unroll
    for (int ky = 0; ky < 3; ++ky)
        #pragma unroll
        for (int kx = 0; kx < 3; ++kx) {
            const unsigned short* ip = vI + (size_t)((y + ky - 1) * 258 + (x + kx - 1)) * 64;
            int wb = ky * 3 + kx;
            for (int c = 0; c < 64; c += 4) {
                ushort4 uv = *(const ushort4*)(ip + c);
                acc += bf2f(uv.x) * wl[c * 9 + wb] + bf2f(uv.y) * wl[(c + 1) * 9 + wb]
                     + bf2f(uv.z) * wl[(c + 2) * 9 + wb] + bf2f(uv.w) * wl[(c + 3) * 9 + wb];
            }
        }
    out[p] = acc;
}

static inline TapOffs zero_toffs() { TapOffs t = {}; return t; }

extern "C" void kernel_launch(void* const* d_in, const int* in_sizes, int n_in,
                              void* d_out, int out_size, void* d_ws, size_t ws_size,
                              hipStream_t stream) {
    const float* x    = (const float*)d_in[0];
    const float* d1w1 = (const float*)d_in[1];  const float* d1b1 = (const float*)d_in[2];
    const float* d1w2 = (const float*)d_in[3];  const float* d1b2 = (const float*)d_in[4];
    const float* d2w1 = (const float*)d_in[5];  const float* d2b1 = (const float*)d_in[6];
    const float* d2w2 = (const float*)d_in[7];  const float* d2b2 = (const float*)d_in[8];
    const float* md1w = (const float*)d_in[9];  const float* md1b = (const float*)d_in[10];
    const float* md2w = (const float*)d_in[11]; const float* md2b = (const float*)d_in[12];
    const float* mbw  = (const float*)d_in[13]; const float* mbb  = (const float*)d_in[14];
    const float* mu1w = (const float*)d_in[15]; const float* mu1b = (const float*)d_in[16];
    const float* mu2w = (const float*)d_in[17]; const float* mu2b = (const float*)d_in[18];
    const float* u3tw = (const float*)d_in[19]; const float* u3tb = (const float*)d_in[20];
    const float* u3w1 = (const float*)d_in[21]; const float* u3b1 = (const float*)d_in[22];
    const float* u3w2 = (const float*)d_in[23]; const float* u3b2 = (const float*)d_in[24];
    const float* u4tw = (const float*)d_in[25]; const float* u4tb = (const float*)d_in[26];
    const float* u4w1 = (const float*)d_in[27]; const float* u4b1 = (const float*)d_in[28];
    const float* u4w2 = (const float*)d_in[29]; const float* u4b2 = (const float*)d_in[30];
    const float* ow   = (const float*)d_in[31]; const float* ob   = (const float*)d_in[32];
    float* out = (float*)d_out;

    unsigned short* W = (unsigned short*)d_ws;

    // ---- flat arena (elem offsets, bf16) ----
    const size_t XCOL = 0;          // 2,097,152
    const size_t A1   = 2097152;    // 258*258*64
    const size_t CAT4 = 6357248;    // 258*258*128
    const size_t P1   = 14877440;   // 130*130*64
    const size_t T2   = 15959040;   // 130*130*128
    const size_t CAT3 = 18122240;   // 130*130*256
    const size_t X0   = 22448640;   // 66*66*128
    const size_t BP1  = 23006208;   // 4608*256
    const size_t BP2  = 24185856;   // 4608*512
    const size_t XB   = 26545152;   // 4608*1024
    const size_t XC   = 31263744;   // 4608*512
    const size_t XD   = 33623040;   // 4608*256
    const size_t V3A  = 34802688;   // 130*130*128
    const size_t V3B  = 36965888;   // 130*130*128
    const size_t V4A  = 39129088;   // 258*258*64
    const size_t V4B  = 43389184;   // 258*258*64
    const size_t AGG  = 47649280;   // 4608*1024
    const size_t WP   = 52367872;   // packed weights 2,320,384

    const size_t a1I   = A1 + 259 * 64;
    const size_t cat4I = CAT4 + 259 * 128;
    const size_t p1I   = P1 + 131 * 64;
    const size_t t2I   = T2 + 131 * 128;
    const size_t cat3I = CAT3 + 131 * 256;
    const size_t X0I   = X0 + 67 * 128;
    const size_t XdI   = XD + 67 * 256;
    const size_t v3aI  = V3A + 131 * 128;
    const size_t v3bI  = V3B + 131 * 128;
    const size_t v4aI  = V4A + 259 * 64;
    const size_t v4bI  = V4B + 259 * 64;

    dim3 blk(TPB);
    const int BIG = 1 << 28;

    // ---- fused pad-ring zeroing ----
    {
        ZArgs za;
        const int off[10] = {(int)A1,(int)CAT4,(int)P1,(int)T2,(int)CAT3,(int)V3A,(int)V3B,(int)V4A,(int)V4B,(int)X0};
        const int w2 [10] = {258,258,130,130,130,130,130,258,258,66};
        const int h2 [10] = {258,258,130,130,130,130,130,258,258,66};
        const int cs [10] = {64,128,64,128,256,128,128,64,64,128};
        int cum = 0;
        for (int i = 0; i < 10; ++i) {
            za.off[i]=off[i]; za.W2[i]=w2[i]; za.H2[i]=h2[i]; za.Cs[i]=cs[i];
            za.cum[i]=cum; cum += (w2[i]*h2[i] - (w2[i]-2)*(h2[i]-2))*cs[i];
        }
        za.cum[10]=cum;
        k_zero_all<<<dim3((cum + TPB - 1) / TPB), blk, 0, stream>>>(za, W, cum);
    }

    // ---- fused weight packing ----
    {
        PackArgs pa;
        const float* ws_[15] = {d1w1,d1w2,d2w1,d2w2,md1w,md2w,mbw,mu1w,mu2w,u3tw,u3w1,u3w2,u4tw,u4w1,u4w2};
        const int mode[15] = {3,0,0,0,1,1,1,1,1,2,0,0,2,0,0};
        const int kc [15] = {1,2,2,4,4,8,16,32,16,8,8,4,4,4,2};
        const int nt [15] = {4,4,8,8,16,32,64,32,16,8,8,8,4,4,4};
        const int kk [15] = {32,64,64,128,128,256,512,1024,512,256,256,128,128,128,64};
        const int nn [15] = {64,64,128,128,256,512,1024,512,256,128,128,128,64,64,64};
        const int tt [15] = {1,9,9,9,1,1,1,1,1,4,9,9,4,9,9};
        int cum = 0;
        for (int i = 0; i < 15; ++i) {
            pa.w[i]=ws_[i]; pa.mode[i]=mode[i]; pa.KC[i]=kc[i]; pa.NT[i]=nt[i];
            pa.K[i]=kk[i]; pa.N[i]=nn[i]; pa.cum[i]=cum;
            cum += tt[i]*kc[i]*nt[i]*512;
        }
        pa.cum[15]=cum;
        k_pack_all<<<dim3((cum + TPB - 1) / TPB), blk, 0, stream>>>(pa, W + WP, cum);
    }
    const size_t pw_d1w1=WP+0, pw_d1w2=WP+2048, pw_d2w1=WP+38912, pw_d2w2=WP+112640,
        pw_md1=WP+260096, pw_md2=WP+292864, pw_mb=WP+423936, pw_mu1=WP+948224,
        pw_mu2=WP+1472512, pw_u3t=WP+1603584, pw_u3w1=WP+1734656, pw_u3w2=WP+2029568,
        pw_u4t=WP+2177024, pw_u4w1=WP+2209792, pw_u4w2=WP+2283520;

    // ---- encoder ----
    k_im2col<<<dim3(8192), blk, 0, stream>>>(x, W + XCOL);
    k_gemm<2,1><<<dim3(512,1), blk, 0, stream>>>(W + XCOL, W + pw_d1w1, d1b1, nullptr, 0,
        W + a1I, 32, 8192, 256, 64, 258*64, 1, zero_toffs(), 4, 1, 0,0,0);
    k_conv3s<1,2><<<dim3(512,1), blk, 0, stream>>>(W + a1I, W + pw_d1w2, d1b2,
        W + cat4I, 258*64, 2, 128, 258*128, 4);
    k_maxpool<<<dim3(1024), blk, 0, stream>>>(W + cat4I, W + p1I, 128, 16, 128, 258*128, 64, 130*64, 128*128*16);
    k_conv3s<1,1><<<dim3(256,2), blk, 0, stream>>>(W + p1I, W + pw_d2w1, d2b1,
        W + t2I, 130*64, 2, 128, 130*128, 8);
    k_conv3s<2,1><<<dim3(256,2), blk, 0, stream>>>(W + t2I, W + pw_d2w2, d2b2,
        W + cat3I, 130*128, 2, 256, 130*256, 8);
    k_maxpool<<<dim3(512), blk, 0, stream>>>(W + cat3I, W + X0I, 64, 32, 256, 130*256, 128, 66*128, 64*64*32);

    // ---- GNN on 66x66 padded grid (K-split GEMMs) ----
    k_gagg<<<dim3(545), blk, 0, stream>>>(W + X0, W + AGG, 128, 4356*32);
    k_gemmS<1><<<dim3(72,4), blk, 0, stream>>>(W + AGG, W + pw_md1, md1b, nullptr, W + BP1, 16);
    k_gagg<<<dim3(1089), blk, 0, stream>>>(W + BP1, W + AGG, 256, 4356*64);
    k_gemmS<2><<<dim3(72,8), blk, 0, stream>>>(W + AGG, W + pw_md2, md2b, nullptr, W + BP2, 32);
    k_gagg<<<dim3(2178), blk, 0, stream>>>(W + BP2, W + AGG, 512, 4356*128);
    k_gemmS<4><<<dim3(72,16), blk, 0, stream>>>(W + AGG, W + pw_mb, mbb, nullptr, W + XB, 64);
    k_gagg<<<dim3(4356), blk, 0, stream>>>(W + XB, W + AGG, 1024, 4356*256);
    k_gemmS<8><<<dim3(72,8), blk, 0, stream>>>(W + AGG, W + pw_mu1, mu1b, W + BP2, W + XC, 32);
    k_gagg<<<dim3(2178), blk, 0, stream>>>(W + XC, W + AGG, 512, 4356*128);
    k_gemmS<4><<<dim3(72,4), blk, 0, stream>>>(W + AGG, W + pw_mu2, mu2b, W + BP1, W + XD, 16);

    // ---- decoder stage 3 ----
    k_gemm<2,8><<<dim3(32,2,4), blk, 0, stream>>>(W + XdI, W + pw_u3t, u3tb, nullptr, 0,
        W + cat3I + 128, 256, 66*256, 64, 512, 2*130*256, 1, zero_toffs(), 8, 0, 1, 130*256, 256);
    k_conv3s<4,1><<<dim3(256,2), blk, 0, stream>>>(W + cat3I, W + pw_u3w1, u3b1,
        W + v3aI, 130*256, 2, 128, 130*128, 8);
    k_conv3s<2,1><<<dim3(256,2), blk, 0, stream>>>(W + v3aI, W + pw_u3w2, u3b2,
        W + v3bI, 130*128, 2, 128, 130*128, 8);

    // ---- decoder stage 4 ----
    k_gemm<2,4><<<dim3(128,1,4), blk, 0, stream>>>(W + v3bI, W + pw_u4t, u4tb, nullptr, 0,
        W + cat4I + 64, 128, 130*128, 128, 256, 2*258*128, 1, zero_toffs(), 4, 0, 1, 258*128, 128);
    k_conv3s<2,2><<<dim3(512,1), blk, 0, stream>>>(W + cat4I, W + pw_u4w1, u4b1,
        W + v4aI, 258*128, 2, 64, 258*64, 4);
    k_conv3s<1,2><<<dim3(512,1), blk, 0, stream>>>(W + v4aI, W + pw_u4w2, u4b2,
        W + v4bI, 258*64, 2, 64, 258*64, 4);

    // ---- output conv 64->1, fp32 ----
    k_outconv<<<dim3(256), blk, 0, stream>>>(W + v4bI, ow, ob, out);
}